// Round 3
// baseline (8510.553 us; speedup 1.0000x reference)
//
#include <hip/hip_runtime.h>

// ---------------------------------------------------------------------------
// LSTM  T=2048, B=64, D=256, H=256  (fp32 in/out, bf16 MFMA compute)
//
//   G[t,b,c] = x[t,b,:] @ Wx[:,c] + bias[c]          (parallel GEMM, fp32 out)
//   per step: pre[c] = G[t,b,c] + h[t-1] @ Wh[:,c]   (persistent recurrent krn)
//   gates f,i,g,o -> c = f*c + i*g ; h = o*tanh(c)
//
// Round-3: round-1 base (G[R][1024] row-major — round-2's transpose split
// 128B lines across g-group WGs on different XCDs, FETCH +88%; reverted) +
// IN-LANE GATE FUSION:
//   * WREC reorders Wh so an MFMA M-tile's 16 rows = 4 cols x 4 gates
//     interleaved (m = 4*cidx + gate). Operands swapped: mfma(Wfrag, hfrag).
//     D layout (col=lane&15=batch, row=(lane>>4)*4+reg) => one lane's 4 acc
//     regs = the 4 gates of ONE (batch,col) element. h B-frag reads from hsm
//     are bit-identical to the old A-frag reads (lane = N-idx + k-group).
//   * gbuf + its barrier round-trip DELETED; combine fully in-lane; publish
//     fires right after each wave's own MFMA chain (waves decoupled through
//     MFMA+combine — publish no longer gated by the slowest wave).
//   * G (incl. bias) staged via a padded LDS tile during the poll: per-thread
//     coalesced dwordx4 issued via asm BEFORE the poll; the poll's vmcnt(0)
//     drains it inside the first (usually failing) RTT — proven hidden.
//   * Reuse-guard barrier placed AFTER the LDS reads / BEFORE MFMA: a fast
//     wave's next-step hsm/gsm writes happen after bar2(t), which all waves
//     (and their reads) have passed. 2 barriers/step, publish path shorter.
//
// Exchange protocol UNCHANGED (round-1 verified): self-describing u32 words
//   word = (tag<<16)|bf16(h), tag = t+1;  agent-scope UC (sc1) path only.
// Poll = 2 concurrent global_load_dwordx4 sc1 + vmcnt(0), retry both on any
// tag miss; "=&v" early-clobber + sched_barrier(0) after waits.
// Per-u32 tags make 16B tearing harmless. Termination: a word cannot advance
// past tag t until this reader's WG publishes t+1 (parity double buffer).
// Overwrite safety: publishing tag t+1 requires having observed tag t from
// ALL slices; tag-(t-1) reads are value-consumed before publishing tag t.
// hbuf MUST be 128 KB (rounds 4/5 hung: 64 KB aliased cstate over live tags).
// Mode-A (same-XCD L2 exchange) abandoned: sc0 polls can cache stale clean
// lines (livelock / silent cross-replay corruption) without L2 inv/wb ops.
// ---------------------------------------------------------------------------

typedef __attribute__((ext_vector_type(8))) short short8;
typedef __attribute__((ext_vector_type(4))) float float4v;
typedef __attribute__((ext_vector_type(4))) unsigned int uint4v;

#define TT   2048
#define BB   64
#define HH   256
#define TBH  ((size_t)33554432)   // T*B*H
#define BH   ((size_t)16384)      // B*H

// workspace layout (bytes)
#define WS_WT    0u          // 1 MB    bf16 WT[1024][512]  (x-part used by gemm)
#define WS_BVEC  1048576u    // 4 KB    fp32 bias[1024]
#define WS_HBUF  1052672u    // 128 KB  u32 hbuf[4][2][16][256] tagged cols
#define WS_CST   1183744u    // 64 KB   fp32 cstate[64][256]
#define WS_WREC  1249280u    // 512 KB  bf16 WREC: recurrent W, MFMA-frag order
#define WS_G     1773568u    // Tc*64*1024*4  fp32 G [R][1024]

__device__ inline unsigned short f2bf(float x) {
    unsigned u = __float_as_uint(x);
    unsigned r = (u + 0x7FFFu + ((u >> 16) & 1u)) >> 16;
    return (unsigned short)r;
}
__device__ inline float sigmoidf_(float x) { return 1.0f / (1.0f + __expf(-x)); }
__device__ inline float tanhf_(float x) {
    float e = __expf(-2.0f * fabsf(x));
    float t = (1.0f - e) / (1.0f + e);
    return copysignf(t, x);
}

// LDS-only workgroup barrier: orders ds ops without draining vmcnt.
__device__ inline void bar_lds() {
    asm volatile("s_waitcnt lgkmcnt(0)\n\ts_barrier" ::: "memory");
}

// ---------------------------------------------------------------------------
// Prep: WT[c][k] = W_gate(c/256)[k][c%256]  (bf16, k in [0,512)), bvec[c]=bias
// (gemm_xw uses only k<256 of WT; h-part kept for simplicity)
// ---------------------------------------------------------------------------
__global__ void k_prep_w(const float* __restrict__ Wf, const float* __restrict__ Wi,
                         const float* __restrict__ Wg, const float* __restrict__ Wo,
                         const float* __restrict__ bf_, const float* __restrict__ bi_,
                         const float* __restrict__ bg_, const float* __restrict__ bo_,
                         unsigned short* __restrict__ WT, float* __restrict__ bvec)
{
    int c = blockIdx.x;            // 0..1023
    int gate = c >> 8, j = c & 255;
    const float* W  = (gate == 0) ? Wf : (gate == 1) ? Wi : (gate == 2) ? Wg : Wo;
    const float* bb = (gate == 0) ? bf_ : (gate == 1) ? bi_ : (gate == 2) ? bg_ : bo_;
    for (int k = threadIdx.x; k < 512; k += 256)
        WT[(size_t)c * 512 + k] = f2bf(W[(size_t)k * 256 + j]);
    if (threadIdx.x == 0) bvec[c] = bb[j];
}

// ---------------------------------------------------------------------------
// Prep recurrent weights in MFMA A-fragment order, gate-interleaved M-rows.
// Block (s*8+wv): slice s (0..7), wave wv (0..7). Fragment for (kk, lane l):
//   m = l&15 -> cidx=(l&15)>>2, gate=l&3;  col = s*32 + wv*4 + cidx
//   k elems = 256 + kk*32 + (l>>4)*8 + e   (recurrent rows of W)
// Layout: WREC[(s*8+wv)*4096 + kk*512 + l*8 + e]  (u16)
// ---------------------------------------------------------------------------
__global__ void k_prep_wrec(const float* __restrict__ Wf, const float* __restrict__ Wi,
                            const float* __restrict__ Wg, const float* __restrict__ Wo,
                            unsigned short* __restrict__ WREC)
{
    int bid = blockIdx.x;          // 0..63
    int slice = bid >> 3, wv = bid & 7;
    for (int idx = threadIdx.x; idx < 512; idx += 256) {
        int kk = idx >> 6, l = idx & 63;
        int col  = slice * 32 + wv * 4 + ((l & 15) >> 2);
        int gate = l & 3;
        const float* W = (gate == 0) ? Wf : (gate == 1) ? Wi : (gate == 2) ? Wg : Wo;
        unsigned short* dst = WREC + (size_t)bid * 4096 + kk * 512 + l * 8;
#pragma unroll
        for (int e = 0; e < 8; ++e) {
            int k = 256 + kk * 32 + (l >> 4) * 8 + e;
            dst[e] = f2bf(W[(size_t)k * 256 + col]);
        }
    }
}

__global__ void k_zero(unsigned int* __restrict__ hbuf, float* __restrict__ cst)
{
    int tid = blockIdx.x * blockDim.x + threadIdx.x;
    int nt = gridDim.x * blockDim.x;
    for (int i = tid; i < 32768; i += nt) hbuf[i] = 0u;  // 128 KB, tag 0 = h_{-1}=0
    for (int i = tid; i < 16384; i += nt) cst[i] = 0.f;  // 64 KB
}

// ---------------------------------------------------------------------------
// Phase 1: G[r][c] = sum_k X[r][k]*WT[c][k] + bvec[c], r = chunk rows (Tc*64)
// 128x128 tile, 4 waves, BK=64, XOR-swizzled LDS, fp32->bf16 on the fly.
// ---------------------------------------------------------------------------
__global__ __launch_bounds__(256) void gemm_xw(
    const float* __restrict__ X,           // chunk base [R][256] fp32
    const unsigned short* __restrict__ WT, // [1024][512] bf16
    const float* __restrict__ bvec,
    float* __restrict__ G)                 // [R][1024] fp32
{
    int col0 = blockIdx.x * 128;
    int row0 = blockIdx.y * 128;
    int tid = threadIdx.x, l = tid & 63, w = tid >> 6;
    int wr = w >> 1, wc = w & 1;

    __shared__ __align__(16) unsigned char asm_[16384];
    __shared__ __align__(16) unsigned char bsm_[16384];

    float4v acc[4][4];
#pragma unroll
    for (int i = 0; i < 4; ++i)
#pragma unroll
        for (int j = 0; j < 4; ++j) { acc[i][j][0] = 0.f; acc[i][j][1] = 0.f; acc[i][j][2] = 0.f; acc[i][j][3] = 0.f; }

    for (int kt = 0; kt < 4; ++kt) {
        // stage A (fp32 -> bf16): 128 rows x 64 k
        {
            int r = tid >> 1, seg = tid & 1;
            const float* src = X + (size_t)(row0 + r) * 256 + kt * 64 + seg * 32;
            short8 tmp[4];
#pragma unroll
            for (int v = 0; v < 4; ++v)
#pragma unroll
                for (int e = 0; e < 8; ++e) tmp[v][e] = (short)f2bf(src[v * 8 + e]);
            unsigned char* dst = asm_ + r * 128;
            int base = seg * 64, swz = (r & 7) << 4;
#pragma unroll
            for (int v = 0; v < 4; ++v)
                *(short8*)(dst + ((base + 16 * v) ^ swz)) = tmp[v];
        }
        // stage B (bf16 copy): 128 cols x 64 k
        {
            int c_ = tid >> 1, seg = tid & 1;
            const unsigned char* src = (const unsigned char*)WT + (size_t)(col0 + c_) * 1024 + kt * 128 + seg * 64;
            unsigned char* dst = bsm_ + c_ * 128;
            int base = seg * 64, swz = (c_ & 7) << 4;
#pragma unroll
            for (int v = 0; v < 4; ++v)
                *(short8*)(dst + ((base + 16 * v) ^ swz)) = *(const short8*)(src + 16 * v);
        }
        __syncthreads();
#pragma unroll
        for (int km = 0; km < 2; ++km) {
            short8 af[4], bfr[4];
            int kb = 16 * (l >> 4) + 64 * km, swz = (l & 7) << 4;
#pragma unroll
            for (int i = 0; i < 4; ++i)
                af[i] = *(const short8*)(asm_ + (wr * 64 + i * 16 + (l & 15)) * 128 + (kb ^ swz));
#pragma unroll
            for (int j = 0; j < 4; ++j)
                bfr[j] = *(const short8*)(bsm_ + (wc * 64 + j * 16 + (l & 15)) * 128 + (kb ^ swz));
#pragma unroll
            for (int i = 0; i < 4; ++i)
#pragma unroll
                for (int j = 0; j < 4; ++j)
                    acc[i][j] = __builtin_amdgcn_mfma_f32_16x16x32_bf16(af[i], bfr[j], acc[i][j], 0, 0, 0);
        }
        __syncthreads();
    }
    // epilogue: + bias, store fp32
#pragma unroll
    for (int j = 0; j < 4; ++j) {
        int col = col0 + wc * 64 + j * 16 + (l & 15);
        float bias = bvec[col];
#pragma unroll
        for (int i = 0; i < 4; ++i) {
            int row = row0 + wr * 64 + i * 16 + (l >> 4) * 4;
            float* Gp = G + (size_t)row * 1024 + col;
            Gp[0]    = acc[i][j][0] + bias;
            Gp[1024] = acc[i][j][1] + bias;
            Gp[2048] = acc[i][j][2] + bias;
            Gp[3072] = acc[i][j][3] + bias;
        }
    }
}

// ---------------------------------------------------------------------------
// Phase 2: persistent recurrent kernel for a chunk of Tc steps.
// Grid 64 blocks x 512 thr; g = wg&7 (>=4 -> exit), s = wg>>3.
// Wave w (0..7): 4 h-cols (s*32 + w*4 .. +4) x 4 gates, K=256.
// Lane l: batch = l&15, col = s*32 + w*4 + (l>>4); acc regs = 4 gates.
// ---------------------------------------------------------------------------
__global__ __launch_bounds__(512) void lstm_rec(
    const float* __restrict__ G,            // [Tc*64][1024] fp32 (chunk)
    const unsigned short* __restrict__ WREC,// frag-ordered recurrent W
    float* __restrict__ out,
    unsigned int* __restrict__ hbuf,        // [4][2][16][256] tagged cols
    float* __restrict__ cstate,             // [64][256] fp32
    int t0, int Tc)
{
    int wg = blockIdx.x;
    int g = wg & 7;
    if (g >= 4) return;
    int s = wg >> 3;                  // 0..7

    int tid = threadIdx.x, l = tid & 63, w = tid >> 6;

    __shared__ __align__(16) unsigned char hsm[8192];   // h tile [16][256] bf16, swizzled
    __shared__ float gsm[4][16][37];                    // G tile [gate][batch][col_in_slice] (+pad)

    // recurrent weights -> registers (A-frags, gate-interleaved M rows)
    short8 aw[8];
    {
        const unsigned short* wp_ = WREC + (size_t)(s * 8 + w) * 4096 + l * 8;
#pragma unroll
        for (int kk = 0; kk < 8; ++kk) aw[kk] = *(const short8*)(wp_ + kk * 512);
    }

    // per-lane output element: batch bl, col colw (4 gates in acc regs)
    int bl = l & 15, cw = l >> 4;
    int colw = s * 32 + w * 4 + cw;
    float creg = cstate[(size_t)(g * 16 + bl) * 256 + colw];

    // poll/staging mapping: row srow (0..15), 8-col block sblk (0..31)
    int srow = tid >> 5, sblk = tid & 31;
    unsigned char* hsm_dst = hsm + srow * 512 + ((sblk * 16) ^ ((srow & 7) << 4));

    // G-tile load mapping: row grow, gate ggate, 4-col group gcol4 (coalesced)
    int grow = tid >> 5, ggate = (tid & 31) >> 3, gcol4 = (tid & 7) * 4;

    for (int tl = 0; tl < Tc; ++tl) {
        int tg = t0 + tl;
        int par = tg & 1, rpar = par ^ 1;

        // G tile load: issue BEFORE poll via asm (drained by poll's vmcnt(0),
        // hidden inside the first poll RTT — round-1 proven).
        float4v gld;
        {
            const float* gp = G + (size_t)(tl * 64 + g * 16 + grow) * 1024 + ggate * 256 + s * 32 + gcol4;
            asm volatile("global_load_dwordx4 %0, %1, off" : "=&v"(gld) : "v"(gp) : "memory");
        }
        // spin-read h_{tg-1}: 2 concurrent dwordx4 sc1 (agent UC) loads,
        // vmcnt(0), retry both on any tag miss (round-1 verified).
        {
            const unsigned int* wp = hbuf + ((size_t)((g * 2 + rpar) * 16) + srow) * 256 + sblk * 8;
            unsigned want = (unsigned)tg;
            short8 hv;
            uint4v w0, w1;
            for (;;) {
                asm volatile("global_load_dwordx4 %0, %2, off sc1\n\t"
                             "global_load_dwordx4 %1, %3, off sc1\n\t"
                             "s_waitcnt vmcnt(0)"
                             : "=&v"(w0), "=&v"(w1)
                             : "v"(wp), "v"(wp + 4) : "memory");
                __builtin_amdgcn_sched_barrier(0);
                if (((w0[0] >> 16) == want) & ((w0[1] >> 16) == want) &
                    ((w0[2] >> 16) == want) & ((w0[3] >> 16) == want) &
                    ((w1[0] >> 16) == want) & ((w1[1] >> 16) == want) &
                    ((w1[2] >> 16) == want) & ((w1[3] >> 16) == want)) break;
            }
            hv[0] = (short)(w0[0] & 0xffffu);
            hv[1] = (short)(w0[1] & 0xffffu);
            hv[2] = (short)(w0[2] & 0xffffu);
            hv[3] = (short)(w0[3] & 0xffffu);
            hv[4] = (short)(w1[0] & 0xffffu);
            hv[5] = (short)(w1[1] & 0xffffu);
            hv[6] = (short)(w1[2] & 0xffffu);
            hv[7] = (short)(w1[3] & 0xffffu);
            *(short8*)hsm_dst = hv;
        }
        // stage G tile to LDS (gld valid: poll did vmcnt(0))
        gsm[ggate][grow][gcol4 + 0] = gld[0];
        gsm[ggate][grow][gcol4 + 1] = gld[1];
        gsm[ggate][grow][gcol4 + 2] = gld[2];
        gsm[ggate][grow][gcol4 + 3] = gld[3];
        bar_lds();   // bar1: hsm + gsm visible
        // LDS reads: h B-frags (bit-identical addressing to old A-frags) + G
        short8 af[8];
        float4v acc, acc1;
        {
            const unsigned char* ap = hsm + bl * 512;
            int kb0 = 16 * (l >> 4), swz = (bl & 7) << 4;
#pragma unroll
            for (int kk = 0; kk < 8; ++kk) af[kk] = *(const short8*)(ap + ((kb0 + 64 * kk) ^ swz));
            acc[0] = gsm[0][bl][w * 4 + cw];
            acc[1] = gsm[1][bl][w * 4 + cw];
            acc[2] = gsm[2][bl][w * 4 + cw];
            acc[3] = gsm[3][bl][w * 4 + cw];
        }
        bar_lds();   // bar2 (reuse guard): all waves' hsm/gsm reads complete
                     // before anyone's next-step writes. Waves run decoupled
                     // through MFMA+combine+publish below.
        // pre = G + Wh(frag) @ h(frag): two independent 4-MFMA chains
        acc1[0] = 0.f; acc1[1] = 0.f; acc1[2] = 0.f; acc1[3] = 0.f;
#pragma unroll
        for (int kk = 0; kk < 4; ++kk) {
            acc  = __builtin_amdgcn_mfma_f32_16x16x32_bf16(aw[kk],     af[kk],     acc,  0, 0, 0);
            acc1 = __builtin_amdgcn_mfma_f32_16x16x32_bf16(aw[kk + 4], af[kk + 4], acc1, 0, 0, 0);
        }
        acc[0] += acc1[0]; acc[1] += acc1[1]; acc[2] += acc1[2]; acc[3] += acc1[3];
        // combine fully in-lane: acc = {f,i,g,o} pre-activations of (bl,colw)
        {
            float f  = sigmoidf_(acc[0]);
            float i  = sigmoidf_(acc[1]);
            float gg = tanhf_(acc[2]);
            float o  = sigmoidf_(acc[3]);
            creg = f * creg + i * gg;
            float h = o * tanhf_(creg);
            // tagged publish ASAP (relaxed, agent): tag = tg+1
            unsigned word = ((unsigned)(tg + 1) << 16) | (unsigned)f2bf(h);
            __hip_atomic_store(hbuf + ((size_t)((g * 2 + par) * 16) + bl) * 256 + colw,
                               word, __ATOMIC_RELAXED, __HIP_MEMORY_SCOPE_AGENT);
            size_t orow = (size_t)tg * 64 + g * 16 + bl;
            out[orow * 256 + colw] = h;
            if (tg == TT - 1) {
                out[TBH + (size_t)(g * 16 + bl) * 256 + colw] = h;
                out[TBH + BH + (size_t)(g * 16 + bl) * 256 + colw] = creg;
            }
        }
        // no end-of-step barrier: next-step hsm/gsm writes happen after this
        // step's bar2, which all waves' LDS reads have passed.
    }
    cstate[(size_t)(g * 16 + bl) * 256 + colw] = creg;
}

// ---------------------------------------------------------------------------
extern "C" void kernel_launch(void* const* d_in, const int* in_sizes, int n_in,
                              void* d_out, int out_size, void* d_ws, size_t ws_size,
                              hipStream_t stream)
{
    (void)in_sizes; (void)n_in; (void)out_size;
    const float* X   = (const float*)d_in[0];
    const float* Wf  = (const float*)d_in[1];
    const float* bf_ = (const float*)d_in[2];
    const float* Wi  = (const float*)d_in[3];
    const float* bi_ = (const float*)d_in[4];
    const float* Wg  = (const float*)d_in[5];
    const float* bg_ = (const float*)d_in[6];
    const float* Wo  = (const float*)d_in[7];
    const float* bo_ = (const float*)d_in[8];
    float* out = (float*)d_out;
    unsigned char* ws = (unsigned char*)d_ws;

    unsigned short* WT   = (unsigned short*)(ws + WS_WT);
    float*          bvec = (float*)(ws + WS_BVEC);
    unsigned int*   hbuf = (unsigned int*)(ws + WS_HBUF);
    float*          cst  = (float*)(ws + WS_CST);
    unsigned short* WREC = (unsigned short*)(ws + WS_WREC);
    float*          G    = (float*)(ws + WS_G);

    size_t avail = ws_size > WS_G ? ws_size - WS_G : 0;
    int Tc = 8;
    const int cands[9] = {2048, 1024, 512, 256, 128, 64, 32, 16, 8};
    for (int i = 0; i < 9; ++i) {
        if ((size_t)cands[i] * 64 * 1024 * 4 <= avail) { Tc = cands[i]; break; }
    }

    k_prep_w<<<1024, 256, 0, stream>>>(Wf, Wi, Wg, Wo, bf_, bi_, bg_, bo_, WT, bvec);
    k_prep_wrec<<<64, 256, 0, stream>>>(Wf, Wi, Wg, Wo, WREC);
    k_zero<<<64, 256, 0, stream>>>(hbuf, cst);

    for (int t0 = 0; t0 < TT; t0 += Tc) {
        int R = Tc * 64;
        gemm_xw<<<dim3(8, R / 128), 256, 0, stream>>>(X + (size_t)t0 * 64 * 256, WT, bvec, G);
        lstm_rec<<<64, 512, 0, stream>>>(G, WREC, out, hbuf, cst, t0, Tc);
    }
}

// Round 4
// 7199.377 us; speedup vs baseline: 1.1821x; 1.1821x over previous
//
#include <hip/hip_runtime.h>

// ---------------------------------------------------------------------------
// LSTM  T=2048, B=64, D=256, H=256  (fp32 in/out, bf16 MFMA compute)
//
//   G[t,b,c] = x[t,b,:] @ Wx[:,c] + bias[c]          (parallel GEMM, fp32 out)
//   per step: pre[c] = G[t,b,c] + h[t-1] @ Wh[:,c]   (persistent recurrent krn)
//   gates f,i,g,o -> c = f*c + i*g ; h = o*tanh(c)
//
// Round-4: round-1 base restored (G[R][1024] row-major, coalesced publish/out,
// gbuf combine — round-3's in-lane fusion scattered the publish/out stores
// 4B/lane over 16 rows: write amp + multi-wave poll windows, 2.3x regression).
// Change: SLICES 8 -> 2 (4 batch-groups x 2 column-slice WGs = 8 WGs x 512).
// Rationale: batches are independent through the recurrence; the exchange tail
// is max over remote publishers. 2 slices => 1 remote party instead of 7.
//   * per WG: 16 batches x 128 h-cols (512 gate-cols); per wave 4 output
//     tiles; weights 32 short8 = 128 VGPR/lane (total ~210 < 256, 8-wave OK).
//   * poll REMOTE-ONLY windows (own half would stall on own store visibility,
//     which bar_lds doesn't drain). Own half written into hsm at combine time
//     via LDS (bf16). tl==0 polls ALL windows (prologue across dispatches).
//   * reader's 8-col window lies inside ONE 128B store of ONE remote wave ->
//     single-shot visibility, minimal tearing.
//   * bar3 deleted: gbuf(t+1) writes happen after bar1(t+1), which requires
//     all waves done with combine(t) gbuf reads; hsm(t+1) staging touches
//     remote cols only (combine owns own cols), af(t) reads done pre-bar2.
//
// Exchange protocol otherwise UNCHANGED (round-1 verified): self-describing
// u32 words, word=(tag<<16)|bf16(h), tag=t+1; agent-scope UC (sc1) path only.
// Poll = 2 concurrent global_load_dwordx4 sc1 + vmcnt(0), retry on tag miss;
// "=&v" early-clobber + sched_barrier(0) after waits. Per-u32 tags make 16B
// tearing harmless. Overwrite safety (2-party form): A overwrites its tag-t+1
// words when publishing t+3 (same parity); before that A observed B's t+2 =>
// B passed bar1 of step t+1 => B consumed A's t+1 words. Termination: words
// advance only after the peer publishes. Proof uses REMOTE observation only,
// so skipping own-window polls does not weaken it.
// hbuf MUST be 128 KB (rounds 4/5 hung: 64 KB aliased cstate over live tags).
// Mode-A (same-XCD L2 exchange) abandoned: sc0 polls can cache stale clean
// lines (livelock / silent cross-replay corruption) without L2 inv/wb ops.
// ---------------------------------------------------------------------------

typedef __attribute__((ext_vector_type(8))) short short8;
typedef __attribute__((ext_vector_type(4))) float float4v;
typedef __attribute__((ext_vector_type(4))) unsigned int uint4v;

#define TT   2048
#define BB   64
#define HH   256
#define TBH  ((size_t)33554432)   // T*B*H
#define BH   ((size_t)16384)      // B*H

// workspace layout (bytes)
#define WS_WT    0u          // 1 MB    bf16 WT[1024][512]
#define WS_BVEC  1048576u    // 4 KB    fp32 bias[1024]
#define WS_HBUF  1052672u    // 128 KB  u32 hbuf[4][2][16][256] tagged cols
#define WS_CST   1183744u    // 64 KB   fp32 cstate[64][256]
#define WS_G     1249280u    // Tc*64*1024*4  fp32 G

__device__ inline unsigned short f2bf(float x) {
    unsigned u = __float_as_uint(x);
    unsigned r = (u + 0x7FFFu + ((u >> 16) & 1u)) >> 16;
    return (unsigned short)r;
}
__device__ inline float sigmoidf_(float x) { return 1.0f / (1.0f + __expf(-x)); }
__device__ inline float tanhf_(float x) {
    float e = __expf(-2.0f * fabsf(x));
    float t = (1.0f - e) / (1.0f + e);
    return copysignf(t, x);
}

// LDS-only workgroup barrier: orders ds ops without draining vmcnt.
__device__ inline void bar_lds() {
    asm volatile("s_waitcnt lgkmcnt(0)\n\ts_barrier" ::: "memory");
}

// ---------------------------------------------------------------------------
// Prep: WT[c][k] = W_gate(c/256)[k][c%256]  (bf16, k in [0,512)), bvec[c]=bias
// ---------------------------------------------------------------------------
__global__ void k_prep_w(const float* __restrict__ Wf, const float* __restrict__ Wi,
                         const float* __restrict__ Wg, const float* __restrict__ Wo,
                         const float* __restrict__ bf_, const float* __restrict__ bi_,
                         const float* __restrict__ bg_, const float* __restrict__ bo_,
                         unsigned short* __restrict__ WT, float* __restrict__ bvec)
{
    int c = blockIdx.x;            // 0..1023
    int gate = c >> 8, j = c & 255;
    const float* W  = (gate == 0) ? Wf : (gate == 1) ? Wi : (gate == 2) ? Wg : Wo;
    const float* bb = (gate == 0) ? bf_ : (gate == 1) ? bi_ : (gate == 2) ? bg_ : bo_;
    for (int k = threadIdx.x; k < 512; k += 256)
        WT[(size_t)c * 512 + k] = f2bf(W[(size_t)k * 256 + j]);
    if (threadIdx.x == 0) bvec[c] = bb[j];
}

__global__ void k_zero(unsigned int* __restrict__ hbuf, float* __restrict__ cst)
{
    int tid = blockIdx.x * blockDim.x + threadIdx.x;
    int nt = gridDim.x * blockDim.x;
    for (int i = tid; i < 32768; i += nt) hbuf[i] = 0u;  // 128 KB, tag 0 = h_{-1}=0
    for (int i = tid; i < 16384; i += nt) cst[i] = 0.f;  // 64 KB
}

// ---------------------------------------------------------------------------
// Phase 1: G[r][c] = sum_k X[r][k]*WT[c][k] + bvec[c], r = chunk rows (Tc*64)
// 128x128 tile, 4 waves, BK=64, XOR-swizzled LDS, fp32->bf16 on the fly.
// ---------------------------------------------------------------------------
__global__ __launch_bounds__(256) void gemm_xw(
    const float* __restrict__ X,           // chunk base [R][256] fp32
    const unsigned short* __restrict__ WT, // [1024][512] bf16
    const float* __restrict__ bvec,
    float* __restrict__ G)                 // [R][1024] fp32
{
    int col0 = blockIdx.x * 128;
    int row0 = blockIdx.y * 128;
    int tid = threadIdx.x, l = tid & 63, w = tid >> 6;
    int wr = w >> 1, wc = w & 1;

    __shared__ __align__(16) unsigned char asm_[16384];
    __shared__ __align__(16) unsigned char bsm_[16384];

    float4v acc[4][4];
#pragma unroll
    for (int i = 0; i < 4; ++i)
#pragma unroll
        for (int j = 0; j < 4; ++j) { acc[i][j][0] = 0.f; acc[i][j][1] = 0.f; acc[i][j][2] = 0.f; acc[i][j][3] = 0.f; }

    for (int kt = 0; kt < 4; ++kt) {
        // stage A (fp32 -> bf16): 128 rows x 64 k
        {
            int r = tid >> 1, seg = tid & 1;
            const float* src = X + (size_t)(row0 + r) * 256 + kt * 64 + seg * 32;
            short8 tmp[4];
#pragma unroll
            for (int v = 0; v < 4; ++v)
#pragma unroll
                for (int e = 0; e < 8; ++e) tmp[v][e] = (short)f2bf(src[v * 8 + e]);
            unsigned char* dst = asm_ + r * 128;
            int base = seg * 64, swz = (r & 7) << 4;
#pragma unroll
            for (int v = 0; v < 4; ++v)
                *(short8*)(dst + ((base + 16 * v) ^ swz)) = tmp[v];
        }
        // stage B (bf16 copy): 128 cols x 64 k
        {
            int c_ = tid >> 1, seg = tid & 1;
            const unsigned char* src = (const unsigned char*)WT + (size_t)(col0 + c_) * 1024 + kt * 128 + seg * 64;
            unsigned char* dst = bsm_ + c_ * 128;
            int base = seg * 64, swz = (c_ & 7) << 4;
#pragma unroll
            for (int v = 0; v < 4; ++v)
                *(short8*)(dst + ((base + 16 * v) ^ swz)) = *(const short8*)(src + 16 * v);
        }
        __syncthreads();
#pragma unroll
        for (int km = 0; km < 2; ++km) {
            short8 af[4], bfr[4];
            int kb = 16 * (l >> 4) + 64 * km, swz = (l & 7) << 4;
#pragma unroll
            for (int i = 0; i < 4; ++i)
                af[i] = *(const short8*)(asm_ + (wr * 64 + i * 16 + (l & 15)) * 128 + (kb ^ swz));
#pragma unroll
            for (int j = 0; j < 4; ++j)
                bfr[j] = *(const short8*)(bsm_ + (wc * 64 + j * 16 + (l & 15)) * 128 + (kb ^ swz));
#pragma unroll
            for (int i = 0; i < 4; ++i)
#pragma unroll
                for (int j = 0; j < 4; ++j)
                    acc[i][j] = __builtin_amdgcn_mfma_f32_16x16x32_bf16(af[i], bfr[j], acc[i][j], 0, 0, 0);
        }
        __syncthreads();
    }
    // epilogue: + bias, store fp32
#pragma unroll
    for (int j = 0; j < 4; ++j) {
        int col = col0 + wc * 64 + j * 16 + (l & 15);
        float bias = bvec[col];
#pragma unroll
        for (int i = 0; i < 4; ++i) {
            int row = row0 + wr * 64 + i * 16 + (l >> 4) * 4;
            float* Gp = G + (size_t)row * 1024 + col;
            Gp[0]    = acc[i][j][0] + bias;
            Gp[1024] = acc[i][j][1] + bias;
            Gp[2048] = acc[i][j][2] + bias;
            Gp[3072] = acc[i][j][3] + bias;
        }
    }
}

// ---------------------------------------------------------------------------
// Phase 2: persistent recurrent kernel for a chunk of Tc steps.
// Grid 8 blocks x 512 thr; g = wg&3 (batch group), s = wg>>2 (slice 0/1).
// Wave w (0..7): gate = w&3, half = w>>2 -> 64 gate-cols as 4 16-col tiles.
// Weights 32 short8 = 128 VGPR/lane.
// ---------------------------------------------------------------------------
__global__ __launch_bounds__(512) void lstm_rec(
    const float* __restrict__ G,            // [Tc*64][1024] fp32 (chunk)
    const unsigned short* __restrict__ WT,  // [1024][512] bf16
    float* __restrict__ out,
    unsigned int* __restrict__ hbuf,        // [4][2][16][256] tagged cols
    float* __restrict__ cstate,             // [64][256] fp32
    int t0, int Tc)
{
    int wg = blockIdx.x;
    int g = wg & 3;                   // batch group 0..3
    int s = wg >> 2;                  // slice 0..1

    int tid = threadIdx.x, l = tid & 63, w = tid >> 6;
    int gate = w & 3, half = w >> 2;
    int lm = l & 15, lh = l >> 4;
    int r04 = lh * 4;

    __shared__ __align__(16) unsigned char hsm[8192];   // h tile [16][256] bf16, swizzled
    __shared__ float gbuf[4][16][128];                  // pre-activations (slice cols)

    // weights -> registers: 4 tiles x 8 k-frags (k bytes [512,1024) of WT row)
    short8 bw[4][8];
#pragma unroll
    for (int jt = 0; jt < 4; ++jt) {
        int c_lane = gate * 256 + s * 128 + half * 64 + jt * 16 + lm;
        const unsigned char* wp_ = (const unsigned char*)WT + (size_t)c_lane * 1024 + 512 + 16 * lh;
#pragma unroll
        for (int kk = 0; kk < 8; ++kk) bw[jt][kk] = *(const short8*)(wp_ + 64 * kk);
    }

    // per-thread combine/publish element: row b_ (0..15), 4 cols j_ + 32k
    int b_ = tid >> 5, j_ = tid & 31;
    float creg[4];
#pragma unroll
    for (int k = 0; k < 4; ++k)
        creg[k] = cstate[(size_t)(g * 16 + b_) * 256 + s * 128 + j_ + 32 * k];

    // poll/staging mapping: row srow (0..15), 8-col window sblk (0..31)
    int srow = tid >> 5, sblk = tid & 31;
    unsigned char* hsm_dst = hsm + srow * 512 + ((sblk * 16) ^ ((srow & 7) << 4));
    bool own = ((sblk >> 4) == s);    // window lies in own slice's 128 cols

    for (int tl = 0; tl < Tc; ++tl) {
        int tg = t0 + tl;
        int par = tg & 1, rpar = par ^ 1;

        // G loads (plain loads; issued before the poll asm, drained by its
        // vmcnt(0) inside the first poll RTT — round-1 proven hidden)
        float4v acc[4];
        {
            const float* Gbase = G + (size_t)(tl * 64 + g * 16) * 1024;
#pragma unroll
            for (int jt = 0; jt < 4; ++jt) {
                int c_lane = gate * 256 + s * 128 + half * 64 + jt * 16 + lm;
#pragma unroll
                for (int k = 0; k < 4; ++k)
                    acc[jt][k] = Gbase[(size_t)(r04 + k) * 1024 + c_lane];
            }
        }
        // spin-read h_{tg-1}: REMOTE windows only (own half comes from LDS,
        // written at combine(t-1)); tl==0 polls ALL windows (cross-dispatch
        // prologue: previous dispatch's tags are drained at kernel exit).
        if ((tl == 0) | (!own)) {
            const unsigned int* wp = hbuf + ((size_t)((g * 2 + rpar) * 16) + srow) * 256 + sblk * 8;
            unsigned want = (unsigned)tg;
            short8 hv;
            uint4v w0, w1;
            for (;;) {
                asm volatile("global_load_dwordx4 %0, %2, off sc1\n\t"
                             "global_load_dwordx4 %1, %3, off sc1\n\t"
                             "s_waitcnt vmcnt(0)"
                             : "=&v"(w0), "=&v"(w1)
                             : "v"(wp), "v"(wp + 4) : "memory");
                __builtin_amdgcn_sched_barrier(0);
                if (((w0[0] >> 16) == want) & ((w0[1] >> 16) == want) &
                    ((w0[2] >> 16) == want) & ((w0[3] >> 16) == want) &
                    ((w1[0] >> 16) == want) & ((w1[1] >> 16) == want) &
                    ((w1[2] >> 16) == want) & ((w1[3] >> 16) == want)) break;
            }
            hv[0] = (short)(w0[0] & 0xffffu);
            hv[1] = (short)(w0[1] & 0xffffu);
            hv[2] = (short)(w0[2] & 0xffffu);
            hv[3] = (short)(w0[3] & 0xffffu);
            hv[4] = (short)(w1[0] & 0xffffu);
            hv[5] = (short)(w1[1] & 0xffffu);
            hv[6] = (short)(w1[2] & 0xffffu);
            hv[7] = (short)(w1[3] & 0xffffu);
            *(short8*)hsm_dst = hv;
        }
        bar_lds();   // bar1: hsm (remote staged + own from combine) visible
        // pre += h @ Wh(cols): af shared across 4 independent tile chains
        {
            const unsigned char* ap = hsm + lm * 512;
            int kb0 = 16 * lh, swz = (lm & 7) << 4;
            short8 af[8];
#pragma unroll
            for (int kk = 0; kk < 8; ++kk) af[kk] = *(const short8*)(ap + ((kb0 + 64 * kk) ^ swz));
#pragma unroll
            for (int kk = 0; kk < 8; ++kk)
#pragma unroll
                for (int jt = 0; jt < 4; ++jt)
                    acc[jt] = __builtin_amdgcn_mfma_f32_16x16x32_bf16(af[kk], bw[jt][kk], acc[jt], 0, 0, 0);
        }
        // publish pre-activations to LDS
#pragma unroll
        for (int jt = 0; jt < 4; ++jt)
#pragma unroll
            for (int k = 0; k < 4; ++k)
                gbuf[gate][r04 + k][half * 64 + jt * 16 + lm] = acc[jt][k];
        bar_lds();   // bar2: gbuf visible; all waves' af reads retired
        // combine: each thread 4 elements (b_, cols j_ + 32k of own slice)
#pragma unroll
        for (int k = 0; k < 4; ++k) {
            int jj = j_ + 32 * k;
            float f  = sigmoidf_(gbuf[0][b_][jj]);
            float i  = sigmoidf_(gbuf[1][b_][jj]);
            float gg = tanhf_(gbuf[2][b_][jj]);
            float o  = sigmoidf_(gbuf[3][b_][jj]);
            creg[k] = f * creg[k] + i * gg;
            float h = o * tanhf_(creg[k]);
            unsigned word = ((unsigned)(tg + 1) << 16) | (unsigned)f2bf(h);
            // tagged publish (relaxed, agent), coalesced 128B per 32 lanes
            __hip_atomic_store(hbuf + ((size_t)((g * 2 + par) * 16) + b_) * 256 + s * 128 + jj,
                               word, __ATOMIC_RELAXED, __HIP_MEMORY_SCOPE_AGENT);
            size_t orow = (size_t)tg * 64 + g * 16 + b_;
            out[orow * 256 + s * 128 + jj] = h;
            // own-half h for next step straight into hsm (bf16, swizzled):
            // safe post-bar2 (all af reads of step t retired); read at t+1
            // after bar1. Swizzle: byte addr XOR bit4, 16B-granule-consistent.
            *(unsigned short*)(hsm + b_ * 512 + ((s * 256 + 2 * jj) ^ ((b_ & 7) << 4))) =
                (unsigned short)(word & 0xffffu);
            if (tg == TT - 1) {
                out[TBH + (size_t)(g * 16 + b_) * 256 + s * 128 + jj] = h;
                out[TBH + BH + (size_t)(g * 16 + b_) * 256 + s * 128 + jj] = creg[k];
            }
        }
        // no bar3: gbuf(t+1) writes happen after bar1(t+1) (requires all waves
        // done combining); hsm(t+1) remote staging doesn't touch own cols;
        // af(t) reads retired before bar2(t).
    }
#pragma unroll
    for (int k = 0; k < 4; ++k)
        cstate[(size_t)(g * 16 + b_) * 256 + s * 128 + j_ + 32 * k] = creg[k];
}

// ---------------------------------------------------------------------------
extern "C" void kernel_launch(void* const* d_in, const int* in_sizes, int n_in,
                              void* d_out, int out_size, void* d_ws, size_t ws_size,
                              hipStream_t stream)
{
    (void)in_sizes; (void)n_in; (void)out_size;
    const float* X   = (const float*)d_in[0];
    const float* Wf  = (const float*)d_in[1];
    const float* bf_ = (const float*)d_in[2];
    const float* Wi  = (const float*)d_in[3];
    const float* bi_ = (const float*)d_in[4];
    const float* Wg  = (const float*)d_in[5];
    const float* bg_ = (const float*)d_in[6];
    const float* Wo  = (const float*)d_in[7];
    const float* bo_ = (const float*)d_in[8];
    float* out = (float*)d_out;
    unsigned char* ws = (unsigned char*)d_ws;

    unsigned short* WT   = (unsigned short*)(ws + WS_WT);
    float*          bvec = (float*)(ws + WS_BVEC);
    unsigned int*   hbuf = (unsigned int*)(ws + WS_HBUF);
    float*          cst  = (float*)(ws + WS_CST);
    float*          G    = (float*)(ws + WS_G);

    size_t avail = ws_size > WS_G ? ws_size - WS_G : 0;
    int Tc = 8;
    const int cands[9] = {2048, 1024, 512, 256, 128, 64, 32, 16, 8};
    for (int i = 0; i < 9; ++i) {
        if ((size_t)cands[i] * 64 * 1024 * 4 <= avail) { Tc = cands[i]; break; }
    }

    k_prep_w<<<1024, 256, 0, stream>>>(Wf, Wi, Wg, Wo, bf_, bi_, bg_, bo_, WT, bvec);
    k_zero<<<64, 256, 0, stream>>>(hbuf, cst);

    for (int t0 = 0; t0 < TT; t0 += Tc) {
        int R = Tc * 64;
        gemm_xw<<<dim3(8, R / 128), 256, 0, stream>>>(X + (size_t)t0 * 64 * 256, WT, bvec, G);
        lstm_rec<<<8, 512, 0, stream>>>(G, WT, out, hbuf, cst, t0, Tc);
    }
}

// Round 5
// 5066.745 us; speedup vs baseline: 1.6797x; 1.4209x over previous
//
#include <hip/hip_runtime.h>

// ---------------------------------------------------------------------------
// LSTM  T=2048, B=64, D=256, H=256  (fp32 in/out, bf16 MFMA compute)
//
//   G[t,b,c] = x[t,b,:] @ Wx[:,c] + bias[c]          (parallel GEMM, fp32 out)
//   per step: pre[c] = G[t,b,c] + h[t-1] @ Wh[:,c]   (persistent recurrent krn)
//   gates f,i,g,o -> c = f*c + i*g ; h = o*tanh(c)
//
// Round-5: re-run round-4's party-reduction at a register-feasible point.
// Round-4 lesson: bw[4][8] needs 128 VGPR; compiler reported 104 => weights
// were rematerialized/spilled and re-read from L2 inside every step's MFMA
// section (step 4180 -> 8130 cy with protocol traffic unchanged). The slice
// experiment was voided by remat, not refuted.
// Config: 4 slices x 4 batch-groups = 16 WGs x 512 thr.
//   * per wave: 2 column-tiles (32 gate-cols), bw[2][8] = 64 VGPR -> resident.
//   * weights loaded via asm volatile global_load_dwordx4 (asm outputs cannot
//     be rematerialized; at ~140 total pressure they stay in registers).
//   * own-slice h via LDS at combine (round-4 verified); poll REMOTE windows
//     only; tl==0 polls ALL windows (cross-dispatch prologue).
//   * publish/out stores stay round-1-coalesced: 32-lane group = 128B line.
//
// Exchange protocol UNCHANGED (round-1 verified): self-describing u32 words,
// word=(tag<<16)|bf16(h), tag=t+1; agent-scope UC (sc1) path only.
// Poll = 2 concurrent global_load_dwordx4 sc1 + vmcnt(0), retry on tag miss;
// "=&v" early-clobber + sched_barrier(0) after waits. Per-u32 tags make 16B
// tearing harmless. Overwrite safety (4-party form): A overwrites its tag-t+1
// words when publishing t+3 (same parity); before that A observed tag t+2
// from ALL slices => each peer passed bar1 of step t+2 => each consumed A's
// t+1 words during step t+1's poll. Proof uses REMOTE observation only, so
// skipping own-window polls does not weaken it. Termination: words advance
// only after peers publish (parity double buffer).
// hbuf MUST be 128 KB (prior sessions hung: 64 KB aliased cstate over tags).
// Mode-A (same-XCD L2 exchange) abandoned: sc0 polls can cache stale clean
// lines (livelock / silent cross-replay corruption) without L2 inv/wb ops.
// ---------------------------------------------------------------------------

typedef __attribute__((ext_vector_type(8))) short short8;
typedef __attribute__((ext_vector_type(4))) float float4v;
typedef __attribute__((ext_vector_type(4))) unsigned int uint4v;

#define TT   2048
#define BB   64
#define HH   256
#define TBH  ((size_t)33554432)   // T*B*H
#define BH   ((size_t)16384)      // B*H

// workspace layout (bytes)
#define WS_WT    0u          // 1 MB    bf16 WT[1024][512]
#define WS_BVEC  1048576u    // 4 KB    fp32 bias[1024]
#define WS_HBUF  1052672u    // 128 KB  u32 hbuf[4][2][16][256] tagged cols
#define WS_CST   1183744u    // 64 KB   fp32 cstate[64][256]
#define WS_G     1249280u    // Tc*64*1024*4  fp32 G

__device__ inline unsigned short f2bf(float x) {
    unsigned u = __float_as_uint(x);
    unsigned r = (u + 0x7FFFu + ((u >> 16) & 1u)) >> 16;
    return (unsigned short)r;
}
__device__ inline float sigmoidf_(float x) { return 1.0f / (1.0f + __expf(-x)); }
__device__ inline float tanhf_(float x) {
    float e = __expf(-2.0f * fabsf(x));
    float t = (1.0f - e) / (1.0f + e);
    return copysignf(t, x);
}

// LDS-only workgroup barrier: orders ds ops without draining vmcnt.
__device__ inline void bar_lds() {
    asm volatile("s_waitcnt lgkmcnt(0)\n\ts_barrier" ::: "memory");
}

// ---------------------------------------------------------------------------
// Prep: WT[c][k] = W_gate(c/256)[k][c%256]  (bf16, k in [0,512)), bvec[c]=bias
// ---------------------------------------------------------------------------
__global__ void k_prep_w(const float* __restrict__ Wf, const float* __restrict__ Wi,
                         const float* __restrict__ Wg, const float* __restrict__ Wo,
                         const float* __restrict__ bf_, const float* __restrict__ bi_,
                         const float* __restrict__ bg_, const float* __restrict__ bo_,
                         unsigned short* __restrict__ WT, float* __restrict__ bvec)
{
    int c = blockIdx.x;            // 0..1023
    int gate = c >> 8, j = c & 255;
    const float* W  = (gate == 0) ? Wf : (gate == 1) ? Wi : (gate == 2) ? Wg : Wo;
    const float* bb = (gate == 0) ? bf_ : (gate == 1) ? bi_ : (gate == 2) ? bg_ : bo_;
    for (int k = threadIdx.x; k < 512; k += 256)
        WT[(size_t)c * 512 + k] = f2bf(W[(size_t)k * 256 + j]);
    if (threadIdx.x == 0) bvec[c] = bb[j];
}

__global__ void k_zero(unsigned int* __restrict__ hbuf, float* __restrict__ cst)
{
    int tid = blockIdx.x * blockDim.x + threadIdx.x;
    int nt = gridDim.x * blockDim.x;
    for (int i = tid; i < 32768; i += nt) hbuf[i] = 0u;  // 128 KB, tag 0 = h_{-1}=0
    for (int i = tid; i < 16384; i += nt) cst[i] = 0.f;  // 64 KB
}

// ---------------------------------------------------------------------------
// Phase 1: G[r][c] = sum_k X[r][k]*WT[c][k] + bvec[c], r = chunk rows (Tc*64)
// 128x128 tile, 4 waves, BK=64, XOR-swizzled LDS, fp32->bf16 on the fly.
// ---------------------------------------------------------------------------
__global__ __launch_bounds__(256) void gemm_xw(
    const float* __restrict__ X,           // chunk base [R][256] fp32
    const unsigned short* __restrict__ WT, // [1024][512] bf16
    const float* __restrict__ bvec,
    float* __restrict__ G)                 // [R][1024] fp32
{
    int col0 = blockIdx.x * 128;
    int row0 = blockIdx.y * 128;
    int tid = threadIdx.x, l = tid & 63, w = tid >> 6;
    int wr = w >> 1, wc = w & 1;

    __shared__ __align__(16) unsigned char asm_[16384];
    __shared__ __align__(16) unsigned char bsm_[16384];

    float4v acc[4][4];
#pragma unroll
    for (int i = 0; i < 4; ++i)
#pragma unroll
        for (int j = 0; j < 4; ++j) { acc[i][j][0] = 0.f; acc[i][j][1] = 0.f; acc[i][j][2] = 0.f; acc[i][j][3] = 0.f; }

    for (int kt = 0; kt < 4; ++kt) {
        // stage A (fp32 -> bf16): 128 rows x 64 k
        {
            int r = tid >> 1, seg = tid & 1;
            const float* src = X + (size_t)(row0 + r) * 256 + kt * 64 + seg * 32;
            short8 tmp[4];
#pragma unroll
            for (int v = 0; v < 4; ++v)
#pragma unroll
                for (int e = 0; e < 8; ++e) tmp[v][e] = (short)f2bf(src[v * 8 + e]);
            unsigned char* dst = asm_ + r * 128;
            int base = seg * 64, swz = (r & 7) << 4;
#pragma unroll
            for (int v = 0; v < 4; ++v)
                *(short8*)(dst + ((base + 16 * v) ^ swz)) = tmp[v];
        }
        // stage B (bf16 copy): 128 cols x 64 k
        {
            int c_ = tid >> 1, seg = tid & 1;
            const unsigned char* src = (const unsigned char*)WT + (size_t)(col0 + c_) * 1024 + kt * 128 + seg * 64;
            unsigned char* dst = bsm_ + c_ * 128;
            int base = seg * 64, swz = (c_ & 7) << 4;
#pragma unroll
            for (int v = 0; v < 4; ++v)
                *(short8*)(dst + ((base + 16 * v) ^ swz)) = *(const short8*)(src + 16 * v);
        }
        __syncthreads();
#pragma unroll
        for (int km = 0; km < 2; ++km) {
            short8 af[4], bfr[4];
            int kb = 16 * (l >> 4) + 64 * km, swz = (l & 7) << 4;
#pragma unroll
            for (int i = 0; i < 4; ++i)
                af[i] = *(const short8*)(asm_ + (wr * 64 + i * 16 + (l & 15)) * 128 + (kb ^ swz));
#pragma unroll
            for (int j = 0; j < 4; ++j)
                bfr[j] = *(const short8*)(bsm_ + (wc * 64 + j * 16 + (l & 15)) * 128 + (kb ^ swz));
#pragma unroll
            for (int i = 0; i < 4; ++i)
#pragma unroll
                for (int j = 0; j < 4; ++j)
                    acc[i][j] = __builtin_amdgcn_mfma_f32_16x16x32_bf16(af[i], bfr[j], acc[i][j], 0, 0, 0);
        }
        __syncthreads();
    }
    // epilogue: + bias, store fp32
#pragma unroll
    for (int j = 0; j < 4; ++j) {
        int col = col0 + wc * 64 + j * 16 + (l & 15);
        float bias = bvec[col];
#pragma unroll
        for (int i = 0; i < 4; ++i) {
            int row = row0 + wr * 64 + i * 16 + (l >> 4) * 4;
            float* Gp = G + (size_t)row * 1024 + col;
            Gp[0]    = acc[i][j][0] + bias;
            Gp[1024] = acc[i][j][1] + bias;
            Gp[2048] = acc[i][j][2] + bias;
            Gp[3072] = acc[i][j][3] + bias;
        }
    }
}

// ---------------------------------------------------------------------------
// Phase 2: persistent recurrent kernel for a chunk of Tc steps.
// Grid 16 blocks x 512 thr; g = wg&3 (batch group), s = wg>>2 (slice 0..3).
// Wave w (0..7): gate = w&3, half = w>>2 -> 32 gate-cols as 2 16-col tiles.
// Weights 16 short8 = 64 VGPR/lane, loaded via asm (remat-proof).
// ---------------------------------------------------------------------------
__global__ __launch_bounds__(512) void lstm_rec(
    const float* __restrict__ G,            // [Tc*64][1024] fp32 (chunk)
    const unsigned short* __restrict__ WT,  // [1024][512] bf16
    float* __restrict__ out,
    unsigned int* __restrict__ hbuf,        // [4][2][16][256] tagged cols
    float* __restrict__ cstate,             // [64][256] fp32
    int t0, int Tc)
{
    int wg = blockIdx.x;
    int g = wg & 3;                   // batch group 0..3
    int s = wg >> 2;                  // slice 0..3

    int tid = threadIdx.x, l = tid & 63, w = tid >> 6;
    int gate = w & 3, half = w >> 2;
    int lm = l & 15, lh = l >> 4;
    int r04 = lh * 4;

    __shared__ __align__(16) unsigned char hsm[8192];   // h tile [16][256] bf16, swizzled
    __shared__ float gbuf[4][16][64];                   // pre-activations (slice cols)

    // weights -> registers: 2 tiles x 8 k-frags (k bytes [512,1024) of WT row)
    // asm loads: outputs cannot be rematerialized -> guaranteed resident.
    short8 bw[2][8];
#pragma unroll
    for (int jt = 0; jt < 2; ++jt) {
        int c_lane = gate * 256 + s * 64 + half * 32 + jt * 16 + lm;
        const unsigned char* wp_ = (const unsigned char*)WT + (size_t)c_lane * 1024 + 512 + 16 * lh;
#pragma unroll
        for (int kk = 0; kk < 8; ++kk)
            asm volatile("global_load_dwordx4 %0, %1, off"
                         : "=&v"(bw[jt][kk]) : "v"(wp_ + 64 * kk) : "memory");
    }
    asm volatile("s_waitcnt vmcnt(0)" ::: "memory");
    __builtin_amdgcn_sched_barrier(0);

    // per-thread combine/publish element: row b_ (0..15), cols j_ and j_+32
    int b_ = tid >> 5, j_ = tid & 31;
    float creg[2];
#pragma unroll
    for (int k = 0; k < 2; ++k)
        creg[k] = cstate[(size_t)(g * 16 + b_) * 256 + s * 64 + j_ + 32 * k];

    // poll/staging mapping: row srow (0..15), 8-col window sblk (0..31)
    int srow = tid >> 5, sblk = tid & 31;
    unsigned char* hsm_dst = hsm + srow * 512 + ((sblk * 16) ^ ((srow & 7) << 4));
    bool own = ((sblk >> 3) == s);    // window lies in own slice's 64 cols

    for (int tl = 0; tl < Tc; ++tl) {
        int tg = t0 + tl;
        int par = tg & 1, rpar = par ^ 1;

        // G loads (plain loads; issued before the poll asm, drained by its
        // vmcnt(0) inside the first poll RTT — round-1 proven hidden)
        float4v acc[2];
        {
            const float* Gbase = G + (size_t)(tl * 64 + g * 16) * 1024;
#pragma unroll
            for (int jt = 0; jt < 2; ++jt) {
                int c_lane = gate * 256 + s * 64 + half * 32 + jt * 16 + lm;
#pragma unroll
                for (int k = 0; k < 4; ++k)
                    acc[jt][k] = Gbase[(size_t)(r04 + k) * 1024 + c_lane];
            }
        }
        // spin-read h_{tg-1}: REMOTE windows only (own slice comes from LDS,
        // written at combine(t-1)); tl==0 polls ALL windows (cross-dispatch
        // prologue: previous dispatch's tags are drained at kernel exit).
        if ((tl == 0) | (!own)) {
            const unsigned int* wp = hbuf + ((size_t)((g * 2 + rpar) * 16) + srow) * 256 + sblk * 8;
            unsigned want = (unsigned)tg;
            short8 hv;
            uint4v w0, w1;
            for (;;) {
                asm volatile("global_load_dwordx4 %0, %2, off sc1\n\t"
                             "global_load_dwordx4 %1, %3, off sc1\n\t"
                             "s_waitcnt vmcnt(0)"
                             : "=&v"(w0), "=&v"(w1)
                             : "v"(wp), "v"(wp + 4) : "memory");
                __builtin_amdgcn_sched_barrier(0);
                if (((w0[0] >> 16) == want) & ((w0[1] >> 16) == want) &
                    ((w0[2] >> 16) == want) & ((w0[3] >> 16) == want) &
                    ((w1[0] >> 16) == want) & ((w1[1] >> 16) == want) &
                    ((w1[2] >> 16) == want) & ((w1[3] >> 16) == want)) break;
            }
            hv[0] = (short)(w0[0] & 0xffffu);
            hv[1] = (short)(w0[1] & 0xffffu);
            hv[2] = (short)(w0[2] & 0xffffu);
            hv[3] = (short)(w0[3] & 0xffffu);
            hv[4] = (short)(w1[0] & 0xffffu);
            hv[5] = (short)(w1[1] & 0xffffu);
            hv[6] = (short)(w1[2] & 0xffffu);
            hv[7] = (short)(w1[3] & 0xffffu);
            *(short8*)hsm_dst = hv;
        }
        bar_lds();   // bar1: hsm (remote staged + own from combine) visible
        // pre += h @ Wh(cols): af shared across 2 independent tile chains
        {
            const unsigned char* ap = hsm + lm * 512;
            int kb0 = 16 * lh, swz = (lm & 7) << 4;
            short8 af[8];
#pragma unroll
            for (int kk = 0; kk < 8; ++kk) af[kk] = *(const short8*)(ap + ((kb0 + 64 * kk) ^ swz));
#pragma unroll
            for (int kk = 0; kk < 8; ++kk)
#pragma unroll
                for (int jt = 0; jt < 2; ++jt)
                    acc[jt] = __builtin_amdgcn_mfma_f32_16x16x32_bf16(af[kk], bw[jt][kk], acc[jt], 0, 0, 0);
        }
        // publish pre-activations to LDS
#pragma unroll
        for (int jt = 0; jt < 2; ++jt)
#pragma unroll
            for (int k = 0; k < 4; ++k)
                gbuf[gate][r04 + k][half * 32 + jt * 16 + lm] = acc[jt][k];
        bar_lds();   // bar2: gbuf visible; all waves' af reads retired
        // combine: each thread 2 elements (b_, cols j_ and j_+32 of own slice)
#pragma unroll
        for (int k = 0; k < 2; ++k) {
            int jj = j_ + 32 * k;
            float f  = sigmoidf_(gbuf[0][b_][jj]);
            float i  = sigmoidf_(gbuf[1][b_][jj]);
            float gg = tanhf_(gbuf[2][b_][jj]);
            float o  = sigmoidf_(gbuf[3][b_][jj]);
            creg[k] = f * creg[k] + i * gg;
            float h = o * tanhf_(creg[k]);
            unsigned word = ((unsigned)(tg + 1) << 16) | (unsigned)f2bf(h);
            // tagged publish (relaxed, agent), coalesced 128B per 32 lanes
            __hip_atomic_store(hbuf + ((size_t)((g * 2 + par) * 16) + b_) * 256 + s * 64 + jj,
                               word, __ATOMIC_RELAXED, __HIP_MEMORY_SCOPE_AGENT);
            size_t orow = (size_t)tg * 64 + g * 16 + b_;
            out[orow * 256 + s * 64 + jj] = h;
            // own-slice h for next step straight into hsm (bf16, swizzled):
            // safe post-bar2 (all af reads of step t retired); read at t+1
            // after bar1. Byte addr XOR bit4 swizzle, 16B-granule-consistent.
            *(unsigned short*)(hsm + b_ * 512 + ((s * 128 + 2 * jj) ^ ((b_ & 7) << 4))) =
                (unsigned short)(word & 0xffffu);
            if (tg == TT - 1) {
                out[TBH + (size_t)(g * 16 + b_) * 256 + s * 64 + jj] = h;
                out[TBH + BH + (size_t)(g * 16 + b_) * 256 + s * 64 + jj] = creg[k];
            }
        }
        // no bar3: gbuf(t+1) writes happen after bar1(t+1) (requires all waves
        // done combining); hsm(t+1) remote staging doesn't touch own cols;
        // af(t) reads retired before bar2(t).
    }
#pragma unroll
    for (int k = 0; k < 2; ++k)
        cstate[(size_t)(g * 16 + b_) * 256 + s * 64 + j_ + 32 * k] = creg[k];
}

// ---------------------------------------------------------------------------
extern "C" void kernel_launch(void* const* d_in, const int* in_sizes, int n_in,
                              void* d_out, int out_size, void* d_ws, size_t ws_size,
                              hipStream_t stream)
{
    (void)in_sizes; (void)n_in; (void)out_size;
    const float* X   = (const float*)d_in[0];
    const float* Wf  = (const float*)d_in[1];
    const float* bf_ = (const float*)d_in[2];
    const float* Wi  = (const float*)d_in[3];
    const float* bi_ = (const float*)d_in[4];
    const float* Wg  = (const float*)d_in[5];
    const float* bg_ = (const float*)d_in[6];
    const float* Wo  = (const float*)d_in[7];
    const float* bo_ = (const float*)d_in[8];
    float* out = (float*)d_out;
    unsigned char* ws = (unsigned char*)d_ws;

    unsigned short* WT   = (unsigned short*)(ws + WS_WT);
    float*          bvec = (float*)(ws + WS_BVEC);
    unsigned int*   hbuf = (unsigned int*)(ws + WS_HBUF);
    float*          cst  = (float*)(ws + WS_CST);
    float*          G    = (float*)(ws + WS_G);

    size_t avail = ws_size > WS_G ? ws_size - WS_G : 0;
    int Tc = 8;
    const int cands[9] = {2048, 1024, 512, 256, 128, 64, 32, 16, 8};
    for (int i = 0; i < 9; ++i) {
        if ((size_t)cands[i] * 64 * 1024 * 4 <= avail) { Tc = cands[i]; break; }
    }

    k_prep_w<<<1024, 256, 0, stream>>>(Wf, Wi, Wg, Wo, bf_, bi_, bg_, bo_, WT, bvec);
    k_zero<<<64, 256, 0, stream>>>(hbuf, cst);

    for (int t0 = 0; t0 < TT; t0 += Tc) {
        int R = Tc * 64;
        gemm_xw<<<dim3(8, R / 128), 256, 0, stream>>>(X + (size_t)t0 * 64 * 256, WT, bvec, G);
        lstm_rec<<<16, 512, 0, stream>>>(G, WT, out, hbuf, cst, t0, Tc);
    }
}

// Round 7
// 3235.684 us; speedup vs baseline: 2.6302x; 1.5659x over previous
//
#include <hip/hip_runtime.h>

// ---------------------------------------------------------------------------
// LSTM  T=2048, B=64, D=256, H=256  (fp32 in/out, bf16 MFMA compute)
//
//   G[t,b,c] = x[t,b,:] @ Wx[:,c] + bias[c]          (parallel GEMM, fp32 out)
//   per step: pre[c] = G[t,b,c] + h[t-1] @ Wh[:,c]   (persistent recurrent krn)
//   gates f,i,g,o -> c = f*c + i*g ; h = o*tanh(c)
//
// Round-7 = EXACT round-1 kernel code (verified 3918us, passed) with ONE
// change: Tc capped at 512 so the G chunk (128 MB) stays Infinity-Cache(L3)-
// resident between gemm_xw (writer) and lstm_rec (reader).
// Rationale: round-1's poll vmcnt(0) FIFO-waits the G loads issued just
// before it; at Tc=1024 (256MB chunk) FETCH=167MB/dispatch => ~65% of G reads
// are HBM misses (~900cy) vs poll RTT ~400-600cy => ~300-500cy exposed/step.
// At Tc=512: G 128MB + out 32MB + X 32MB ~= 195MB < 256MB L3 => G reads hit
// L3 (~200-300cy) and hide under the poll RTT with ZERO kernel changes.
// Validation counter: FETCH_SIZE per rec dispatch must drop 167MB -> <50MB.
// Round-6 lesson (FAILED, absmax 0.38): one-step-ahead G prefetch via asm
// output registers is NOT spill-safe (compiler may spill/move a pending asm
// output before our vmcnt(0), capturing garbage). Do not re-introduce async
// asm-held register prefetch without proving no spills.
//
// Recurrent kernel: 4 batch-groups (M=16) x 8 column-slice WGs (128 cols each).
// h exchange FENCE-FREE via self-describing u32 words:
//   word = (tag << 16) | bf16(h),  tag = t+1  (tags <= 2048 < 2^16)
// All exchange traffic uses the agent-scope UC path (bypasses per-XCD L2s ->
// correct for ANY workgroup placement; no L2-residency staleness, no fences).
// Poll = 2 CONCURRENT global_load_dwordx4 sc1 per thread (4 tagged u32 each),
// one vmcnt(0), retry both on any tag miss. "=&v" early-clobber +
// sched_barrier(0) after waits (round-8 lesson of prior session).
// Per-u32 tags make 16B tearing harmless. Termination: a word cannot advance
// past tag t until this reader's WG publishes t+1 (parity double buffer).
// Overwrite safety: publishing tag t+1 requires having observed tag t from
// ALL slices (via staging barrier) => all finished reading tag t-1.
// In-loop barriers are s_waitcnt lgkmcnt(0); s_barrier (LDS-only ordering for
// hsm/gbuf); publish/out store-acks drain inside the next poll's vmcnt(0),
// overlapped with the poll load RTT. Stale self-reads fail the tag check and
// retry (self-healing).
// hbuf MUST be 128 KB (earlier sessions hung: 64 KB aliased cstate over tags).
// Mode-A (same-XCD L2 exchange) abandoned: sc0 polls can cache stale clean
// lines (livelock / silent cross-replay corruption) without L2 inv/wb ops.
// ---------------------------------------------------------------------------

typedef __attribute__((ext_vector_type(8))) short short8;
typedef __attribute__((ext_vector_type(4))) float float4v;
typedef __attribute__((ext_vector_type(4))) unsigned int uint4v;

#define TT   2048
#define BB   64
#define HH   256
#define TBH  ((size_t)33554432)   // T*B*H
#define BH   ((size_t)16384)      // B*H

// workspace layout (bytes)
#define WS_WT    0u          // 1 MB    bf16 WT[1024][512]
#define WS_BVEC  1048576u    // 4 KB    fp32 bias[1024]
#define WS_HBUF  1052672u    // 128 KB  u32 hbuf[4][2][16][256] tagged cols
#define WS_CST   1183744u    // 64 KB   fp32 cstate[64][256]
#define WS_G     1249280u    // Tc*64*1024*4  fp32 G

__device__ inline unsigned short f2bf(float x) {
    unsigned u = __float_as_uint(x);
    unsigned r = (u + 0x7FFFu + ((u >> 16) & 1u)) >> 16;
    return (unsigned short)r;
}
__device__ inline float sigmoidf_(float x) { return 1.0f / (1.0f + __expf(-x)); }
__device__ inline float tanhf_(float x) {
    float e = __expf(-2.0f * fabsf(x));
    float t = (1.0f - e) / (1.0f + e);
    return copysignf(t, x);
}

// LDS-only workgroup barrier: orders ds ops (hsm/gbuf) without draining
// vmcnt (publish/out store-acks stay in flight across the barrier).
// Single asm block => "memory" clobber fences compiler motion on both sides.
__device__ inline void bar_lds() {
    asm volatile("s_waitcnt lgkmcnt(0)\n\ts_barrier" ::: "memory");
}

// ---------------------------------------------------------------------------
// Prep: WT[c][k] = W_gate(c/256)[k][c%256]  (bf16, k in [0,512)), bvec[c]=bias
// ---------------------------------------------------------------------------
__global__ void k_prep_w(const float* __restrict__ Wf, const float* __restrict__ Wi,
                         const float* __restrict__ Wg, const float* __restrict__ Wo,
                         const float* __restrict__ bf_, const float* __restrict__ bi_,
                         const float* __restrict__ bg_, const float* __restrict__ bo_,
                         unsigned short* __restrict__ WT, float* __restrict__ bvec)
{
    int c = blockIdx.x;            // 0..1023
    int gate = c >> 8, j = c & 255;
    const float* W  = (gate == 0) ? Wf : (gate == 1) ? Wi : (gate == 2) ? Wg : Wo;
    const float* bb = (gate == 0) ? bf_ : (gate == 1) ? bi_ : (gate == 2) ? bg_ : bo_;
    for (int k = threadIdx.x; k < 512; k += 256)
        WT[(size_t)c * 512 + k] = f2bf(W[(size_t)k * 256 + j]);
    if (threadIdx.x == 0) bvec[c] = bb[j];
}

__global__ void k_zero(unsigned int* __restrict__ hbuf, float* __restrict__ cst)
{
    int tid = blockIdx.x * blockDim.x + threadIdx.x;
    int nt = gridDim.x * blockDim.x;
    for (int i = tid; i < 32768; i += nt) hbuf[i] = 0u;  // 128 KB, tag 0 = h_{-1}=0
    for (int i = tid; i < 16384; i += nt) cst[i] = 0.f;  // 64 KB
}

// ---------------------------------------------------------------------------
// Phase 1: G[r][c] = sum_k X[r][k]*WT[c][k] + bvec[c], r = chunk rows (Tc*64)
// 128x128 tile, 4 waves, BK=64, XOR-swizzled LDS, fp32->bf16 on the fly.
// ---------------------------------------------------------------------------
__global__ __launch_bounds__(256) void gemm_xw(
    const float* __restrict__ X,           // chunk base [R][256] fp32
    const unsigned short* __restrict__ WT, // [1024][512] bf16
    const float* __restrict__ bvec,
    float* __restrict__ G)                 // [R][1024] fp32
{
    int col0 = blockIdx.x * 128;
    int row0 = blockIdx.y * 128;
    int tid = threadIdx.x, l = tid & 63, w = tid >> 6;
    int wr = w >> 1, wc = w & 1;

    __shared__ __align__(16) unsigned char asm_[16384];
    __shared__ __align__(16) unsigned char bsm_[16384];

    float4v acc[4][4];
#pragma unroll
    for (int i = 0; i < 4; ++i)
#pragma unroll
        for (int j = 0; j < 4; ++j) { acc[i][j][0] = 0.f; acc[i][j][1] = 0.f; acc[i][j][2] = 0.f; acc[i][j][3] = 0.f; }

    for (int kt = 0; kt < 4; ++kt) {
        // stage A (fp32 -> bf16): 128 rows x 64 k
        {
            int r = tid >> 1, seg = tid & 1;
            const float* src = X + (size_t)(row0 + r) * 256 + kt * 64 + seg * 32;
            short8 tmp[4];
#pragma unroll
            for (int v = 0; v < 4; ++v)
#pragma unroll
                for (int e = 0; e < 8; ++e) tmp[v][e] = (short)f2bf(src[v * 8 + e]);
            unsigned char* dst = asm_ + r * 128;
            int base = seg * 64, swz = (r & 7) << 4;
#pragma unroll
            for (int v = 0; v < 4; ++v)
                *(short8*)(dst + ((base + 16 * v) ^ swz)) = tmp[v];
        }
        // stage B (bf16 copy): 128 cols x 64 k
        {
            int c_ = tid >> 1, seg = tid & 1;
            const unsigned char* src = (const unsigned char*)WT + (size_t)(col0 + c_) * 1024 + kt * 128 + seg * 64;
            unsigned char* dst = bsm_ + c_ * 128;
            int base = seg * 64, swz = (c_ & 7) << 4;
#pragma unroll
            for (int v = 0; v < 4; ++v)
                *(short8*)(dst + ((base + 16 * v) ^ swz)) = *(const short8*)(src + 16 * v);
        }
        __syncthreads();
#pragma unroll
        for (int km = 0; km < 2; ++km) {
            short8 af[4], bfr[4];
            int kb = 16 * (l >> 4) + 64 * km, swz = (l & 7) << 4;
#pragma unroll
            for (int i = 0; i < 4; ++i)
                af[i] = *(const short8*)(asm_ + (wr * 64 + i * 16 + (l & 15)) * 128 + (kb ^ swz));
#pragma unroll
            for (int j = 0; j < 4; ++j)
                bfr[j] = *(const short8*)(bsm_ + (wc * 64 + j * 16 + (l & 15)) * 128 + (kb ^ swz));
#pragma unroll
            for (int i = 0; i < 4; ++i)
#pragma unroll
                for (int j = 0; j < 4; ++j)
                    acc[i][j] = __builtin_amdgcn_mfma_f32_16x16x32_bf16(af[i], bfr[j], acc[i][j], 0, 0, 0);
        }
        __syncthreads();
    }
    // epilogue: + bias, store fp32
#pragma unroll
    for (int j = 0; j < 4; ++j) {
        int col = col0 + wc * 64 + j * 16 + (l & 15);
        float bias = bvec[col];
#pragma unroll
        for (int i = 0; i < 4; ++i) {
            int row = row0 + wr * 64 + i * 16 + (l >> 4) * 4;
            float* Gp = G + (size_t)row * 1024 + col;
            Gp[0]    = acc[i][j][0] + bias;
            Gp[1024] = acc[i][j][1] + bias;
            Gp[2048] = acc[i][j][2] + bias;
            Gp[3072] = acc[i][j][3] + bias;
        }
    }
}

// ---------------------------------------------------------------------------
// Phase 2: persistent recurrent kernel for a chunk of Tc steps.
// Grid 64 blocks x 512 thr; g = wg&7 (>=4 -> exit), s = wg>>3.
// Wave w: gate = w&3, dh = w>>2 -> 16 cols; weights in 32 VGPRs/lane.
// ---------------------------------------------------------------------------
__global__ __launch_bounds__(512) void lstm_rec(
    const float* __restrict__ G,            // [Tc*64][1024] fp32 (chunk)
    const unsigned short* __restrict__ WT,  // [1024][512] bf16
    float* __restrict__ out,
    unsigned int* __restrict__ hbuf,        // [4][2][16][256] tagged cols
    float* __restrict__ cstate,             // [64][256] fp32
    int t0, int Tc)
{
    int wg = blockIdx.x;
    int g = wg & 7;
    if (g >= 4) return;
    int s = wg >> 3;                  // 0..7

    int tid = threadIdx.x, l = tid & 63, w = tid >> 6;
    int gate = w & 3, dh = w >> 2;
    int c_lane = gate * 256 + s * 32 + dh * 16 + (l & 15);

    __shared__ __align__(16) unsigned char hsm[8192];   // h tile [16][256] bf16, swizzled
    __shared__ float gbuf[4][16][32];                   // pre-activations

    // weights -> registers: k bytes [512,1024) of WT row c_lane
    short8 bw[8];
    {
        const unsigned char* wp_ = (const unsigned char*)WT + (size_t)c_lane * 1024 + 512 + 16 * (l >> 4);
#pragma unroll
        for (int kk = 0; kk < 8; ++kk) bw[kk] = *(const short8*)(wp_ + 64 * kk);
    }

    // per-thread combine/publish element: row b_ (0..15), col j_ (0..31)
    int b_ = tid >> 5, j_ = tid & 31;
    float creg = cstate[(size_t)(g * 16 + b_) * 256 + s * 32 + j_];

    // poll/staging mapping: row srow (0..15), 8-col block sblk (0..31)
    int srow = tid >> 5, sblk = tid & 31;
    unsigned char* hsm_dst = hsm + srow * 512 + ((sblk * 16) ^ ((srow & 7) << 4));

    for (int tl = 0; tl < Tc; ++tl) {
        int tg = t0 + tl;
        int par = tg & 1, rpar = par ^ 1;

        // G preload (independent of h -> in flight during poll round 1;
        // at Tc=512 the chunk is L3-resident => ~200-300cy, fully hidden)
        float4v acc;
        {
            const float* Gp = G + (size_t)(tl * 64 + g * 16) * 1024 + c_lane;
            int r0 = (l >> 4) * 4;
            acc[0] = Gp[(size_t)(r0 + 0) * 1024];
            acc[1] = Gp[(size_t)(r0 + 1) * 1024];
            acc[2] = Gp[(size_t)(r0 + 2) * 1024];
            acc[3] = Gp[(size_t)(r0 + 3) * 1024];
        }
        // spin-read h_{tg-1}: 2 CONCURRENT dwordx4 sc1 (agent UC) loads,
        // one vmcnt(0) (also drains prior publish/out store-acks, overlapped
        // with the load RTT); retry both on any tag miss, 2 outstanding max.
        {
            const unsigned int* wp = hbuf + ((size_t)((g * 2 + rpar) * 16) + srow) * 256 + sblk * 8;
            unsigned want = (unsigned)tg;
            short8 hv;
            uint4v w0, w1;
            for (;;) {
                asm volatile("global_load_dwordx4 %0, %2, off sc1\n\t"
                             "global_load_dwordx4 %1, %3, off sc1\n\t"
                             "s_waitcnt vmcnt(0)"
                             : "=&v"(w0), "=&v"(w1)
                             : "v"(wp), "v"(wp + 4) : "memory");
                __builtin_amdgcn_sched_barrier(0);
                if (((w0[0] >> 16) == want) & ((w0[1] >> 16) == want) &
                    ((w0[2] >> 16) == want) & ((w0[3] >> 16) == want) &
                    ((w1[0] >> 16) == want) & ((w1[1] >> 16) == want) &
                    ((w1[2] >> 16) == want) & ((w1[3] >> 16) == want)) break;
            }
            hv[0] = (short)(w0[0] & 0xffffu);
            hv[1] = (short)(w0[1] & 0xffffu);
            hv[2] = (short)(w0[2] & 0xffffu);
            hv[3] = (short)(w0[3] & 0xffffu);
            hv[4] = (short)(w1[0] & 0xffffu);
            hv[5] = (short)(w1[1] & 0xffffu);
            hv[6] = (short)(w1[2] & 0xffffu);
            hv[7] = (short)(w1[3] & 0xffffu);
            *(short8*)hsm_dst = hv;
        }
        bar_lds();   // hsm writes visible; no vmcnt drain (stores stay in flight)
        // pre += h @ Wh(cols): two independent 4-MFMA chains
        {
            int row = l & 15;
            const unsigned char* ap = hsm + row * 512;
            int kb0 = 16 * (l >> 4), swz = (row & 7) << 4;
            short8 af[8];
#pragma unroll
            for (int kk = 0; kk < 8; ++kk) af[kk] = *(const short8*)(ap + ((kb0 + 64 * kk) ^ swz));
            float4v acc1 = {0.f, 0.f, 0.f, 0.f};
#pragma unroll
            for (int kk = 0; kk < 4; ++kk) {
                acc  = __builtin_amdgcn_mfma_f32_16x16x32_bf16(af[kk],     bw[kk],     acc,  0, 0, 0);
                acc1 = __builtin_amdgcn_mfma_f32_16x16x32_bf16(af[kk + 4], bw[kk + 4], acc1, 0, 0, 0);
            }
            acc[0] += acc1[0]; acc[1] += acc1[1]; acc[2] += acc1[2]; acc[3] += acc1[3];
        }
        // publish pre-activations to LDS
        {
            int r0 = (l >> 4) * 4, cc = dh * 16 + (l & 15);
            gbuf[gate][r0 + 0][cc] = acc[0];
            gbuf[gate][r0 + 1][cc] = acc[1];
            gbuf[gate][r0 + 2][cc] = acc[2];
            gbuf[gate][r0 + 3][cc] = acc[3];
        }
        bar_lds();   // gbuf writes visible
        // combine: all 512 threads, one (b_, j_) element each
        {
            float f  = sigmoidf_(gbuf[0][b_][j_]);
            float i  = sigmoidf_(gbuf[1][b_][j_]);
            float gg = tanhf_(gbuf[2][b_][j_]);
            float o  = sigmoidf_(gbuf[3][b_][j_]);
            creg = f * creg + i * gg;
            float h = o * tanhf_(creg);
            // tagged publish ASAP (relaxed, agent): tag = tg+1
            unsigned word = ((unsigned)(tg + 1) << 16) | (unsigned)f2bf(h);
            __hip_atomic_store(hbuf + ((size_t)((g * 2 + par) * 16) + b_) * 256 + s * 32 + j_,
                               word, __ATOMIC_RELAXED, __HIP_MEMORY_SCOPE_AGENT);
            size_t orow = (size_t)tg * 64 + g * 16 + b_;
            out[orow * 256 + s * 32 + j_] = h;
            if (tg == TT - 1) {
                out[TBH + (size_t)(g * 16 + b_) * 256 + s * 32 + j_] = h;
                out[TBH + BH + (size_t)(g * 16 + b_) * 256 + s * 32 + j_] = creg;
            }
        }
        bar_lds();   // protects hsm/gbuf reuse; publish/out store-acks drain
                     // in background (next poll's vmcnt(0) picks them up).
                     // Tag protocol needs no cross-WG drain here: stale
                     // self-reads fail the tag check and retry.
    }
    cstate[(size_t)(g * 16 + b_) * 256 + s * 32 + j_] = creg;
}

// ---------------------------------------------------------------------------
extern "C" void kernel_launch(void* const* d_in, const int* in_sizes, int n_in,
                              void* d_out, int out_size, void* d_ws, size_t ws_size,
                              hipStream_t stream)
{
    (void)in_sizes; (void)n_in; (void)out_size;
    const float* X   = (const float*)d_in[0];
    const float* Wf  = (const float*)d_in[1];
    const float* bf_ = (const float*)d_in[2];
    const float* Wi  = (const float*)d_in[3];
    const float* bi_ = (const float*)d_in[4];
    const float* Wg  = (const float*)d_in[5];
    const float* bg_ = (const float*)d_in[6];
    const float* Wo  = (const float*)d_in[7];
    const float* bo_ = (const float*)d_in[8];
    float* out = (float*)d_out;
    unsigned char* ws = (unsigned char*)d_ws;

    unsigned short* WT   = (unsigned short*)(ws + WS_WT);
    float*          bvec = (float*)(ws + WS_BVEC);
    unsigned int*   hbuf = (unsigned int*)(ws + WS_HBUF);
    float*          cst  = (float*)(ws + WS_CST);
    float*          G    = (float*)(ws + WS_G);

    // Tc capped at 512: G chunk 128MB stays L3-resident between gemm (writer)
    // and lstm_rec (reader) -> G reads hit Infinity Cache, hidden under poll.
    size_t avail = ws_size > WS_G ? ws_size - WS_G : 0;
    int Tc = 8;
    const int cands[7] = {512, 256, 128, 64, 32, 16, 8};
    for (int i = 0; i < 7; ++i) {
        if ((size_t)cands[i] * 64 * 1024 * 4 <= avail) { Tc = cands[i]; break; }
    }

    k_prep_w<<<1024, 256, 0, stream>>>(Wf, Wi, Wg, Wo, bf_, bi_, bg_, bo_, WT, bvec);
    k_zero<<<64, 256, 0, stream>>>(hbuf, cst);

    for (int t0 = 0; t0 < TT; t0 += Tc) {
        int R = Tc * 64;
        gemm_xw<<<dim3(8, R / 128), 256, 0, stream>>>(X + (size_t)t0 * 64 * 256, WT, bvec, G);
        lstm_rec<<<64, 512, 0, stream>>>(G, WT, out, hbuf, cst, t0, Tc);
    }
}

// Round 9
// 3214.496 us; speedup vs baseline: 2.6476x; 1.0066x over previous
//
#include <hip/hip_runtime.h>

// ---------------------------------------------------------------------------
// LSTM  T=2048, B=64, D=256, H=256  (fp32 in/out, bf16 MFMA compute)
//
//   G[t,b,c] = x[t,b,:] @ Wx[:,c] + bias[c]          (parallel GEMM)
//   per step: pre[c] = G[t,b,c] + h[t-1] @ Wh[:,c]   (persistent recurrent krn)
//   gates f,i,g,o -> c = f*c + i*g ; h = o*tanh(c)
//
// Round-9 = round-8 with the ushort4 -> ushort4v rename (HIP predefines
// ushort4 in amd_hip_vector_types.h; round-8 failed to compile, no perf info).
// Round-8 = round-7 (verified 3236us: round-1 structure + Tc=512) with ONE
// change: G stored as PACKED BF16, layout G2[R/4][1024][4] (the 4 row-values
// of a column contiguous).
//   * rec G read: 4 strided dword loads -> ONE 8B load (4x fewer ops in the
//     FIFO ahead of the poll's vmcnt(0); round-7 showed the G term is
//     latency- not residency-dominated: FETCH stayed chunk-proportional).
//   * G chunk 64MB at Tc=512 (well inside L3); gemm epilogue stores halve.
//   * bf16->f32 convert pinned AFTER the poll via empty asm "+v"(gv) dep
//     (else MachineLICM hoists convert + its waitcnt above the poll,
//     re-exposing G latency). Load can't sink past the poll's "memory"
//     clobber. NO other changes (round-6 lesson: no bundling, no asm-held
//     register pipelining).
// Accuracy: bf16 G adds ~0.4% rel error to pre-activations; margin was 4.2x
// (0.0039 vs 0.0163). If absmax fails -> revert to fp32 G.
//
// Recurrent kernel: 4 batch-groups (M=16) x 8 column-slice WGs (128 cols each).
// h exchange FENCE-FREE via self-describing u32 words:
//   word = (tag << 16) | bf16(h),  tag = t+1  (tags <= 2048 < 2^16)
// All exchange traffic uses the agent-scope UC path (bypasses per-XCD L2s ->
// correct for ANY workgroup placement; no L2-residency staleness, no fences).
// Poll = 2 CONCURRENT global_load_dwordx4 sc1 per thread (4 tagged u32 each),
// one vmcnt(0), retry both on any tag miss. "=&v" early-clobber +
// sched_barrier(0) after waits. Per-u32 tags make 16B tearing harmless.
// Termination: a word cannot advance past tag t until this reader's WG
// publishes t+1 (parity double buffer). Overwrite safety: publishing tag t+1
// requires having observed tag t from ALL slices => all finished reading t-1.
// In-loop barriers are s_waitcnt lgkmcnt(0); s_barrier (LDS-only ordering);
// publish/out store-acks drain inside the next poll's vmcnt(0).
// hbuf MUST be 128 KB (earlier sessions hung: 64 KB aliased cstate over tags).
// Mode-A (same-XCD L2 exchange) abandoned: sc0 polls can cache stale clean
// lines (livelock / silent cross-replay corruption) without L2 inv/wb ops.
// Round-6 lesson (FAILED): asm-held async register prefetch is not spill-safe.
// ---------------------------------------------------------------------------

typedef __attribute__((ext_vector_type(8))) short short8;
typedef __attribute__((ext_vector_type(4))) float float4v;
typedef __attribute__((ext_vector_type(4))) unsigned int uint4v;
typedef __attribute__((ext_vector_type(4))) unsigned short ushort4v;

#define TT   2048
#define BB   64
#define HH   256
#define TBH  ((size_t)33554432)   // T*B*H
#define BH   ((size_t)16384)      // B*H

// workspace layout (bytes)
#define WS_WT    0u          // 1 MB    bf16 WT[1024][512]
#define WS_BVEC  1048576u    // 4 KB    fp32 bias[1024]
#define WS_HBUF  1052672u    // 128 KB  u32 hbuf[4][2][16][256] tagged cols
#define WS_CST   1183744u    // 64 KB   fp32 cstate[64][256]
#define WS_G     1249280u    // Tc*64*1024*2  bf16 G2 [R/4][1024][4]

__device__ inline unsigned short f2bf(float x) {
    unsigned u = __float_as_uint(x);
    unsigned r = (u + 0x7FFFu + ((u >> 16) & 1u)) >> 16;
    return (unsigned short)r;
}
__device__ inline float bf2f(unsigned short x) {
    return __uint_as_float((unsigned)x << 16);
}
__device__ inline float sigmoidf_(float x) { return 1.0f / (1.0f + __expf(-x)); }
__device__ inline float tanhf_(float x) {
    float e = __expf(-2.0f * fabsf(x));
    float t = (1.0f - e) / (1.0f + e);
    return copysignf(t, x);
}

// LDS-only workgroup barrier: orders ds ops (hsm/gbuf) without draining
// vmcnt (publish/out store-acks stay in flight across the barrier).
__device__ inline void bar_lds() {
    asm volatile("s_waitcnt lgkmcnt(0)\n\ts_barrier" ::: "memory");
}

// ---------------------------------------------------------------------------
// Prep: WT[c][k] = W_gate(c/256)[k][c%256]  (bf16, k in [0,512)), bvec[c]=bias
// ---------------------------------------------------------------------------
__global__ void k_prep_w(const float* __restrict__ Wf, const float* __restrict__ Wi,
                         const float* __restrict__ Wg, const float* __restrict__ Wo,
                         const float* __restrict__ bf_, const float* __restrict__ bi_,
                         const float* __restrict__ bg_, const float* __restrict__ bo_,
                         unsigned short* __restrict__ WT, float* __restrict__ bvec)
{
    int c = blockIdx.x;            // 0..1023
    int gate = c >> 8, j = c & 255;
    const float* W  = (gate == 0) ? Wf : (gate == 1) ? Wi : (gate == 2) ? Wg : Wo;
    const float* bb = (gate == 0) ? bf_ : (gate == 1) ? bi_ : (gate == 2) ? bg_ : bo_;
    for (int k = threadIdx.x; k < 512; k += 256)
        WT[(size_t)c * 512 + k] = f2bf(W[(size_t)k * 256 + j]);
    if (threadIdx.x == 0) bvec[c] = bb[j];
}

__global__ void k_zero(unsigned int* __restrict__ hbuf, float* __restrict__ cst)
{
    int tid = blockIdx.x * blockDim.x + threadIdx.x;
    int nt = gridDim.x * blockDim.x;
    for (int i = tid; i < 32768; i += nt) hbuf[i] = 0u;  // 128 KB, tag 0 = h_{-1}=0
    for (int i = tid; i < 16384; i += nt) cst[i] = 0.f;  // 64 KB
}

// ---------------------------------------------------------------------------
// Phase 1: G2[r>>2][c][r&3] = bf16( sum_k X[r][k]*WT[c][k] + bvec[c] )
// 128x128 tile, 4 waves, BK=64, XOR-swizzled LDS, fp32->bf16 on the fly.
// ---------------------------------------------------------------------------
__global__ __launch_bounds__(256) void gemm_xw(
    const float* __restrict__ X,           // chunk base [R][256] fp32
    const unsigned short* __restrict__ WT, // [1024][512] bf16
    const float* __restrict__ bvec,
    unsigned short* __restrict__ G2)       // [R/4][1024][4] bf16 packed
{
    int col0 = blockIdx.x * 128;
    int row0 = blockIdx.y * 128;
    int tid = threadIdx.x, l = tid & 63, w = tid >> 6;
    int wr = w >> 1, wc = w & 1;

    __shared__ __align__(16) unsigned char asm_[16384];
    __shared__ __align__(16) unsigned char bsm_[16384];

    float4v acc[4][4];
#pragma unroll
    for (int i = 0; i < 4; ++i)
#pragma unroll
        for (int j = 0; j < 4; ++j) { acc[i][j][0] = 0.f; acc[i][j][1] = 0.f; acc[i][j][2] = 0.f; acc[i][j][3] = 0.f; }

    for (int kt = 0; kt < 4; ++kt) {
        // stage A (fp32 -> bf16): 128 rows x 64 k
        {
            int r = tid >> 1, seg = tid & 1;
            const float* src = X + (size_t)(row0 + r) * 256 + kt * 64 + seg * 32;
            short8 tmp[4];
#pragma unroll
            for (int v = 0; v < 4; ++v)
#pragma unroll
                for (int e = 0; e < 8; ++e) tmp[v][e] = (short)f2bf(src[v * 8 + e]);
            unsigned char* dst = asm_ + r * 128;
            int base = seg * 64, swz = (r & 7) << 4;
#pragma unroll
            for (int v = 0; v < 4; ++v)
                *(short8*)(dst + ((base + 16 * v) ^ swz)) = tmp[v];
        }
        // stage B (bf16 copy): 128 cols x 64 k
        {
            int c_ = tid >> 1, seg = tid & 1;
            const unsigned char* src = (const unsigned char*)WT + (size_t)(col0 + c_) * 1024 + kt * 128 + seg * 64;
            unsigned char* dst = bsm_ + c_ * 128;
            int base = seg * 64, swz = (c_ & 7) << 4;
#pragma unroll
            for (int v = 0; v < 4; ++v)
                *(short8*)(dst + ((base + 16 * v) ^ swz)) = *(const short8*)(src + 16 * v);
        }
        __syncthreads();
#pragma unroll
        for (int km = 0; km < 2; ++km) {
            short8 af[4], bfr[4];
            int kb = 16 * (l >> 4) + 64 * km, swz = (l & 7) << 4;
#pragma unroll
            for (int i = 0; i < 4; ++i)
                af[i] = *(const short8*)(asm_ + (wr * 64 + i * 16 + (l & 15)) * 128 + (kb ^ swz));
#pragma unroll
            for (int j = 0; j < 4; ++j)
                bfr[j] = *(const short8*)(bsm_ + (wc * 64 + j * 16 + (l & 15)) * 128 + (kb ^ swz));
#pragma unroll
            for (int i = 0; i < 4; ++i)
#pragma unroll
                for (int j = 0; j < 4; ++j)
                    acc[i][j] = __builtin_amdgcn_mfma_f32_16x16x32_bf16(af[i], bfr[j], acc[i][j], 0, 0, 0);
        }
        __syncthreads();
    }
    // epilogue: + bias, pack 4 row-values to bf16, one 8B store each
#pragma unroll
    for (int j = 0; j < 4; ++j) {
        int col = col0 + wc * 64 + j * 16 + (l & 15);
        float bias = bvec[col];
#pragma unroll
        for (int i = 0; i < 4; ++i) {
            int row = row0 + wr * 64 + i * 16 + (l >> 4) * 4;   // row % 4 == 0
            ushort4v v;
            v[0] = f2bf(acc[i][j][0] + bias);
            v[1] = f2bf(acc[i][j][1] + bias);
            v[2] = f2bf(acc[i][j][2] + bias);
            v[3] = f2bf(acc[i][j][3] + bias);
            *(ushort4v*)(G2 + ((size_t)(row >> 2) * 1024 + col) * 4) = v;
        }
    }
}

// ---------------------------------------------------------------------------
// Phase 2: persistent recurrent kernel for a chunk of Tc steps.
// Grid 64 blocks x 512 thr; g = wg&7 (>=4 -> exit), s = wg>>3.
// Wave w: gate = w&3, dh = w>>2 -> 16 cols; weights in 32 VGPRs/lane.
// ---------------------------------------------------------------------------
__global__ __launch_bounds__(512) void lstm_rec(
    const unsigned short* __restrict__ G2,  // [Tc*16][1024][4] bf16 packed
    const unsigned short* __restrict__ WT,  // [1024][512] bf16
    float* __restrict__ out,
    unsigned int* __restrict__ hbuf,        // [4][2][16][256] tagged cols
    float* __restrict__ cstate,             // [64][256] fp32
    int t0, int Tc)
{
    int wg = blockIdx.x;
    int g = wg & 7;
    if (g >= 4) return;
    int s = wg >> 3;                  // 0..7

    int tid = threadIdx.x, l = tid & 63, w = tid >> 6;
    int gate = w & 3, dh = w >> 2;
    int c_lane = gate * 256 + s * 32 + dh * 16 + (l & 15);

    __shared__ __align__(16) unsigned char hsm[8192];   // h tile [16][256] bf16, swizzled
    __shared__ float gbuf[4][16][32];                   // pre-activations

    // weights -> registers: k bytes [512,1024) of WT row c_lane
    short8 bw[8];
    {
        const unsigned char* wp_ = (const unsigned char*)WT + (size_t)c_lane * 1024 + 512 + 16 * (l >> 4);
#pragma unroll
        for (int kk = 0; kk < 8; ++kk) bw[kk] = *(const short8*)(wp_ + 64 * kk);
    }

    // per-thread combine/publish element: row b_ (0..15), col j_ (0..31)
    int b_ = tid >> 5, j_ = tid & 31;
    float creg = cstate[(size_t)(g * 16 + b_) * 256 + s * 32 + j_];

    // poll/staging mapping: row srow (0..15), 8-col block sblk (0..31)
    int srow = tid >> 5, sblk = tid & 31;
    unsigned char* hsm_dst = hsm + srow * 512 + ((sblk * 16) ^ ((srow & 7) << 4));

    for (int tl = 0; tl < Tc; ++tl) {
        int tg = t0 + tl;
        int par = tg & 1, rpar = par ^ 1;

        // G preload: ONE 8B packed load (4 row-values of c_lane), issued
        // before the poll; in flight during the poll RTT, drained by the
        // poll's vmcnt(0). Convert AFTER the poll (pinned below).
        ushort4v gv;
        {
            const unsigned short* Gp = G2 +
                (((size_t)((tl * 64 + g * 16) >> 2) + (l >> 4)) * 1024 + c_lane) * 4;
            gv = *(const ushort4v*)Gp;
        }
        // spin-read h_{tg-1}: 2 CONCURRENT dwordx4 sc1 (agent UC) loads,
        // one vmcnt(0) (also drains the G load + prior store-acks, all
        // overlapped with the load RTT); retry both on any tag miss.
        {
            const unsigned int* wp = hbuf + ((size_t)((g * 2 + rpar) * 16) + srow) * 256 + sblk * 8;
            unsigned want = (unsigned)tg;
            short8 hv;
            uint4v w0, w1;
            for (;;) {
                asm volatile("global_load_dwordx4 %0, %2, off sc1\n\t"
                             "global_load_dwordx4 %1, %3, off sc1\n\t"
                             "s_waitcnt vmcnt(0)"
                             : "=&v"(w0), "=&v"(w1)
                             : "v"(wp), "v"(wp + 4) : "memory");
                __builtin_amdgcn_sched_barrier(0);
                if (((w0[0] >> 16) == want) & ((w0[1] >> 16) == want) &
                    ((w0[2] >> 16) == want) & ((w0[3] >> 16) == want) &
                    ((w1[0] >> 16) == want) & ((w1[1] >> 16) == want) &
                    ((w1[2] >> 16) == want) & ((w1[3] >> 16) == want)) break;
            }
            hv[0] = (short)(w0[0] & 0xffffu);
            hv[1] = (short)(w0[1] & 0xffffu);
            hv[2] = (short)(w0[2] & 0xffffu);
            hv[3] = (short)(w0[3] & 0xffffu);
            hv[4] = (short)(w1[0] & 0xffffu);
            hv[5] = (short)(w1[1] & 0xffffu);
            hv[6] = (short)(w1[2] & 0xffffu);
            hv[7] = (short)(w1[3] & 0xffffu);
            *(short8*)hsm_dst = hv;
        }
        // pin gv consumption AFTER the poll (blocks MachineLICM hoisting the
        // convert + its waitcnt above the poll); poll's vmcnt(0) made gv valid.
        asm volatile("" : "+v"(gv));
        float4v acc;
        acc[0] = bf2f(gv[0]);
        acc[1] = bf2f(gv[1]);
        acc[2] = bf2f(gv[2]);
        acc[3] = bf2f(gv[3]);
        bar_lds();   // hsm writes visible; no vmcnt drain (stores stay in flight)
        // pre += h @ Wh(cols): two independent 4-MFMA chains
        {
            int row = l & 15;
            const unsigned char* ap = hsm + row * 512;
            int kb0 = 16 * (l >> 4), swz = (row & 7) << 4;
            short8 af[8];
#pragma unroll
            for (int kk = 0; kk < 8; ++kk) af[kk] = *(const short8*)(ap + ((kb0 + 64 * kk) ^ swz));
            float4v acc1 = {0.f, 0.f, 0.f, 0.f};
#pragma unroll
            for (int kk = 0; kk < 4; ++kk) {
                acc  = __builtin_amdgcn_mfma_f32_16x16x32_bf16(af[kk],     bw[kk],     acc,  0, 0, 0);
                acc1 = __builtin_amdgcn_mfma_f32_16x16x32_bf16(af[kk + 4], bw[kk + 4], acc1, 0, 0, 0);
            }
            acc[0] += acc1[0]; acc[1] += acc1[1]; acc[2] += acc1[2]; acc[3] += acc1[3];
        }
        // publish pre-activations to LDS
        {
            int r0 = (l >> 4) * 4, cc = dh * 16 + (l & 15);
            gbuf[gate][r0 + 0][cc] = acc[0];
            gbuf[gate][r0 + 1][cc] = acc[1];
            gbuf[gate][r0 + 2][cc] = acc[2];
            gbuf[gate][r0 + 3][cc] = acc[3];
        }
        bar_lds();   // gbuf writes visible
        // combine: all 512 threads, one (b_, j_) element each
        {
            float f  = sigmoidf_(gbuf[0][b_][j_]);
            float i  = sigmoidf_(gbuf[1][b_][j_]);
            float gg = tanhf_(gbuf[2][b_][j_]);
            float o  = sigmoidf_(gbuf[3][b_][j_]);
            creg = f * creg + i * gg;
            float h = o * tanhf_(creg);
            // tagged publish ASAP (relaxed, agent): tag = tg+1
            unsigned word = ((unsigned)(tg + 1) << 16) | (unsigned)f2bf(h);
            __hip_atomic_store(hbuf + ((size_t)((g * 2 + par) * 16) + b_) * 256 + s * 32 + j_,
                               word, __ATOMIC_RELAXED, __HIP_MEMORY_SCOPE_AGENT);
            size_t orow = (size_t)tg * 64 + g * 16 + b_;
            out[orow * 256 + s * 32 + j_] = h;
            if (tg == TT - 1) {
                out[TBH + (size_t)(g * 16 + b_) * 256 + s * 32 + j_] = h;
                out[TBH + BH + (size_t)(g * 16 + b_) * 256 + s * 32 + j_] = creg;
            }
        }
        bar_lds();   // protects hsm/gbuf reuse; publish/out store-acks drain
                     // in background (next poll's vmcnt(0) picks them up).
    }
    cstate[(size_t)(g * 16 + b_) * 256 + s * 32 + j_] = creg;
}

// ---------------------------------------------------------------------------
extern "C" void kernel_launch(void* const* d_in, const int* in_sizes, int n_in,
                              void* d_out, int out_size, void* d_ws, size_t ws_size,
                              hipStream_t stream)
{
    (void)in_sizes; (void)n_in; (void)out_size;
    const float* X   = (const float*)d_in[0];
    const float* Wf  = (const float*)d_in[1];
    const float* bf_ = (const float*)d_in[2];
    const float* Wi  = (const float*)d_in[3];
    const float* bi_ = (const float*)d_in[4];
    const float* Wg  = (const float*)d_in[5];
    const float* bg_ = (const float*)d_in[6];
    const float* Wo  = (const float*)d_in[7];
    const float* bo_ = (const float*)d_in[8];
    float* out = (float*)d_out;
    unsigned char* ws = (unsigned char*)d_ws;

    unsigned short* WT   = (unsigned short*)(ws + WS_WT);
    float*          bvec = (float*)(ws + WS_BVEC);
    unsigned int*   hbuf = (unsigned int*)(ws + WS_HBUF);
    float*          cst  = (float*)(ws + WS_CST);
    unsigned short* G2   = (unsigned short*)(ws + WS_G);

    // Tc capped at 512: bf16 G chunk = 64 MB, L3-resident between gemm
    // (writer) and lstm_rec (reader).
    size_t avail = ws_size > WS_G ? ws_size - WS_G : 0;
    int Tc = 8;
    const int cands[7] = {512, 256, 128, 64, 32, 16, 8};
    for (int i = 0; i < 7; ++i) {
        if ((size_t)cands[i] * 64 * 1024 * 2 <= avail) { Tc = cands[i]; break; }
    }

    k_prep_w<<<1024, 256, 0, stream>>>(Wf, Wi, Wg, Wo, bf_, bi_, bg_, bo_, WT, bvec);
    k_zero<<<64, 256, 0, stream>>>(hbuf, cst);

    for (int t0 = 0; t0 < TT; t0 += Tc) {
        int R = Tc * 64;
        gemm_xw<<<dim3(8, R / 128), 256, 0, stream>>>(X + (size_t)t0 * 64 * 256, WT, bvec, G2);
        lstm_rec<<<64, 512, 0, stream>>>(G2, WT, out, hbuf, cst, t0, Tc);
    }
}